// Round 1
// baseline (5188.087 us; speedup 1.0000x reference)
//
#include <hip/hip_runtime.h>
#include <math.h>

#define D_DIM 1024
#define CL 512   // scan chunk length

// ---------------------------------------------------------------------------
// GEMM (f32, NT): C[m,e] = sum_d A[m,d] * W[e,d]
// A: [M x 1024] row-major, W: [1024 x 1024] row-major, C: [M x 1024]
// Tile 128x128, BK=8, 256 threads, 8x8 outputs/thread.
// ---------------------------------------------------------------------------
__global__ __launch_bounds__(256) void gemm_nt(const float* __restrict__ A,
                                               const float* __restrict__ W,
                                               float* __restrict__ C) {
    __shared__ float As[8][132];
    __shared__ float Bs[8][132];
    const int tid  = threadIdx.x;
    const int row0 = blockIdx.x * 128;
    const int col0 = blockIdx.y * 128;
    const int tx = tid & 15, ty = tid >> 4;
    const int lr = tid >> 1, lc = (tid & 1) * 4;   // stage: 128 rows x 8 cols as float4
    const float* Ap = A + (size_t)(row0 + lr) * D_DIM + lc;
    const float* Wp = W + (size_t)(col0 + lr) * D_DIM + lc;
    float acc[8][8] = {};
    for (int k0 = 0; k0 < D_DIM; k0 += 8) {
        float4 av = *(const float4*)(Ap + k0);
        float4 wv = *(const float4*)(Wp + k0);
        __syncthreads();
        As[lc + 0][lr] = av.x; As[lc + 1][lr] = av.y;
        As[lc + 2][lr] = av.z; As[lc + 3][lr] = av.w;
        Bs[lc + 0][lr] = wv.x; Bs[lc + 1][lr] = wv.y;
        Bs[lc + 2][lr] = wv.z; Bs[lc + 3][lr] = wv.w;
        __syncthreads();
#pragma unroll
        for (int kk = 0; kk < 8; ++kk) {
            float a_[8], b_[8];
#pragma unroll
            for (int i = 0; i < 8; ++i) a_[i] = As[kk][ty * 8 + i];
#pragma unroll
            for (int j = 0; j < 8; ++j) b_[j] = Bs[kk][tx * 8 + j];
#pragma unroll
            for (int i = 0; i < 8; ++i)
#pragma unroll
                for (int j = 0; j < 8; ++j)
                    acc[i][j] = fmaf(a_[i], b_[j], acc[i][j]);
        }
    }
#pragma unroll
    for (int i = 0; i < 8; ++i) {
        float* Cp = C + (size_t)(row0 + ty * 8 + i) * D_DIM + col0 + tx * 8;
        float4 v0 = {acc[i][0], acc[i][1], acc[i][2], acc[i][3]};
        float4 v1 = {acc[i][4], acc[i][5], acc[i][6], acc[i][7]};
        *(float4*)Cp       = v0;
        *(float4*)(Cp + 4) = v1;
    }
}

// ---------------------------------------------------------------------------
// Router p: p[l] = 0.5*(1 - cos(q_full[l-1], k_full[l]))  for l in 1..L-1
// One block (256 threads) per position; 3 simultaneous reductions over D=1024.
// ---------------------------------------------------------------------------
__global__ __launch_bounds__(256) void router_p(const float* __restrict__ q,
                                                const float* __restrict__ k,
                                                float* __restrict__ p) {
    const int l = blockIdx.x + 1;
    const float4* qr = (const float4*)(q + (size_t)(l - 1) * D_DIM);
    const float4* kr = (const float4*)(k + (size_t)l * D_DIM);
    float4 a = qr[threadIdx.x];
    float4 b = kr[threadIdx.x];
    float dot = a.x * b.x + a.y * b.y + a.z * b.z + a.w * b.w;
    float nq  = a.x * a.x + a.y * a.y + a.z * a.z + a.w * a.w;
    float nk  = b.x * b.x + b.y * b.y + b.z * b.z + b.w * b.w;
#pragma unroll
    for (int off = 32; off > 0; off >>= 1) {
        dot += __shfl_down(dot, off);
        nq  += __shfl_down(nq,  off);
        nk  += __shfl_down(nk,  off);
    }
    __shared__ float red[3][4];
    const int w = threadIdx.x >> 6;
    if ((threadIdx.x & 63) == 0) { red[0][w] = dot; red[1][w] = nq; red[2][w] = nk; }
    __syncthreads();
    if (threadIdx.x == 0) {
        dot = red[0][0] + red[0][1] + red[0][2] + red[0][3];
        nq  = red[1][0] + red[1][1] + red[1][2] + red[1][3];
        nk  = red[2][0] + red[2][1] + red[2][2] + red[2][3];
        float dn = fmaxf(sqrtf(nq), 1e-12f) * fmaxf(sqrtf(nk), 1e-12f);
        p[l] = 0.5f * (1.f - dot / dn);
    }
}

// ---------------------------------------------------------------------------
// finalize: a[l], bs[l] from p + sequence starts. (st==1 exactly, so unused.)
// ---------------------------------------------------------------------------
__global__ void finalize_pab(const float* __restrict__ p, const int* __restrict__ cu,
                             int nseq, float* __restrict__ a, float* __restrict__ bs,
                             int L) {
    int l = blockIdx.x * 256 + threadIdx.x;
    if (l >= L) return;
    bool start = false;
    for (int s = 0; s < nseq; ++s) start = start || (cu[s] == l);
    float pv;
    if (l == 0) pv = 1.f;
    else        pv = p[l];
    if (start)  pv = 1.f;
    bool mask = pv > 0.5f;
    float pc  = fminf(fmaxf(pv, 1e-4f), 1.f - 1e-4f);
    a[l]  = start ? 0.f : (mask ? (1.f - pc) : 1.f);
    bs[l] = mask ? pc : 0.f;
}

// ---------------------------------------------------------------------------
// Scan phase A: chunk-local scan of h = a*h + bs*m, in-place over m.
// Also: chunk-local inclusive prefix products P[l] (scalar, thread 0 of dblk 0).
// grid: (nchunks, D/256)
// ---------------------------------------------------------------------------
__global__ __launch_bounds__(256) void scan_local(const float* __restrict__ a,
                                                  const float* __restrict__ bs,
                                                  float* __restrict__ m,
                                                  float* __restrict__ P) {
    __shared__ float a_s[CL], b_s[CL];
    const int chunk = blockIdx.x;
    const int d     = blockIdx.y * 256 + threadIdx.x;
    const int l0    = chunk * CL;
    for (int i = threadIdx.x; i < CL; i += 256) { a_s[i] = a[l0 + i]; b_s[i] = bs[l0 + i]; }
    __syncthreads();
    if (blockIdx.y == 0 && threadIdx.x == 0) {
        float pp = 1.f;
        for (int i = 0; i < CL; ++i) { pp *= a_s[i]; P[l0 + i] = pp; }
    }
    float h = 0.f;
    float* mp = m + (size_t)l0 * D_DIM + d;
    for (int i = 0; i < CL; ++i) {
        float mv = mp[(size_t)i * D_DIM];
        h = fmaf(a_s[i], h, b_s[i] * mv);
        mp[(size_t)i * D_DIM] = h;
    }
}

// ---------------------------------------------------------------------------
// Scan phase B: carry chain over chunks. A_c = P[chunk end] (0 at seq-start
// chunks since a=0 there, so sequence resets propagate automatically).
// grid: D/256 blocks.
// ---------------------------------------------------------------------------
__global__ void scan_carry(const float* __restrict__ y, const float* __restrict__ P,
                           float* __restrict__ carry, int nchunks) {
    const int d = blockIdx.x * 256 + threadIdx.x;
    float H = 0.f;
    for (int c = 0; c < nchunks; ++c) {
        carry[(size_t)c * D_DIM + d] = H;
        const float Ac = P[c * CL + (CL - 1)];
        const float Bc = y[((size_t)c * CL + (CL - 1)) * D_DIM + d];
        H = fmaf(Ac, H, Bc);
    }
}

// ---------------------------------------------------------------------------
// Scan phase C + fuse: y = y_local + P[l]*carry_in[chunk] + residual (in place)
// ---------------------------------------------------------------------------
__global__ void fixup_fuse(float* __restrict__ y, const float* __restrict__ P,
                           const float* __restrict__ carry, const float* __restrict__ res) {
    const size_t i4  = (size_t)blockIdx.x * 256 + threadIdx.x;
    const size_t idx = i4 * 4;
    const int l  = (int)(idx >> 10);          // idx / 1024
    const int dd = (int)(idx & 1023);
    const int c  = l / CL;
    const float pl = P[l];
    float4 yv = *(float4*)(y + idx);
    const float4 cv = *(const float4*)(carry + (size_t)c * D_DIM + dd);
    const float4 rv = *(const float4*)(res + idx);
    yv.x = fmaf(pl, cv.x, yv.x) + rv.x;
    yv.y = fmaf(pl, cv.y, yv.y) + rv.y;
    yv.z = fmaf(pl, cv.z, yv.z) + rv.z;
    yv.w = fmaf(pl, cv.w, yv.w) + rv.w;
    *(float4*)(y + idx) = yv;
}

// ---------------------------------------------------------------------------
extern "C" void kernel_launch(void* const* d_in, const int* in_sizes, int n_in,
                              void* d_out, int out_size, void* d_ws, size_t ws_size,
                              hipStream_t stream) {
    const float* x  = (const float*)d_in[0];
    const float* Wq = (const float*)d_in[1];
    const float* Wk = (const float*)d_in[2];
    const float* Wr = (const float*)d_in[3];
    const float* We = (const float*)d_in[4];
    const float* Wm = (const float*)d_in[5];
    const float* Wd = (const float*)d_in[6];
    const int*   cu = (const int*)d_in[7];
    const int L    = in_sizes[0] / D_DIM;      // 32768
    const int nseq = in_sizes[7] - 1;          // 4
    float* out = (float*)d_out;

    char*  ws  = (char*)d_ws;
    const size_t LD4 = (size_t)L * D_DIM * sizeof(float);
    float* enc   = (float*)ws;                 // [L,D]
    float* bufA  = (float*)(ws + LD4);         // [L,D]: q_raw -> m -> y
    float* p     = (float*)(ws + 2 * LD4);     // [L]
    float* av    = p  + L;                     // [L]
    float* bs    = av + L;                     // [L]
    float* P     = bs + L;                     // [L]
    float* carry = P  + L;                     // [nchunks, D]
    const int nchunks = L / CL;                // 64
    float* kbuf = out;                         // d_out doubles as scratch (k_raw)
    float* res  = out;                         // then residual

    dim3 gg(L / 128, D_DIM / 128);

    // 1. enc = x @ We^T
    gemm_nt<<<gg, 256, 0, stream>>>(x, We, enc);
    // 2. q_raw = enc @ Wq^T ; k_raw = enc @ Wk^T (k in d_out)
    gemm_nt<<<gg, 256, 0, stream>>>(enc, Wq, bufA);
    gemm_nt<<<gg, 256, 0, stream>>>(enc, Wk, kbuf);
    // 3. router p
    router_p<<<L - 1, 256, 0, stream>>>(bufA, kbuf, p);
    finalize_pab<<<(L + 255) / 256, 256, 0, stream>>>(p, cu, nseq, av, bs, L);
    // 4. m = enc @ Wm^T ; residual = enc @ Wr^T (residual in d_out)
    gemm_nt<<<gg, 256, 0, stream>>>(enc, Wm, bufA);
    gemm_nt<<<gg, 256, 0, stream>>>(enc, Wr, res);
    // 5. chunked scan (in place over m) + fuse residual
    dim3 gsl(nchunks, D_DIM / 256);
    scan_local<<<gsl, 256, 0, stream>>>(av, bs, bufA, P);
    scan_carry<<<D_DIM / 256, 256, 0, stream>>>(bufA, P, carry, nchunks);
    fixup_fuse<<<(size_t)L * D_DIM / 4 / 256, 256, 0, stream>>>(bufA, P, carry, res);
    // 6. out = (y + residual) @ Wd^T
    gemm_nt<<<gg, 256, 0, stream>>>(bufA, Wd, out);
}

// Round 2
// 3072.800 us; speedup vs baseline: 1.6884x; 1.6884x over previous
//
#include <hip/hip_runtime.h>
#include <math.h>

#define D_DIM 1024
#define CL 512   // scan chunk length

typedef __attribute__((ext_vector_type(8))) short short8;
typedef __attribute__((ext_vector_type(4))) float f32x4;

__device__ __forceinline__ unsigned short f2bf(float f) {
    unsigned int u = __float_as_uint(f);
    u += 0x7fff + ((u >> 16) & 1);          // round-to-nearest-even
    return (unsigned short)(u >> 16);
}

#define GLOAD16(g, l) __builtin_amdgcn_global_load_lds(                      \
        (const __attribute__((address_space(1))) void*)(g),                  \
        (__attribute__((address_space(3))) void*)(l), 16, 0, 0)

// ---------------------------------------------------------------------------
// f32 GEMM (NT): C[m,e] = sum_d A[m,d] * W[e,d].  Router chain (needs f32).
// 128x128 tile, BK=8, 256 thr. Wave-local 8x8 lane grid -> LDS reads are
// 8-lane broadcasts with 2-way bank aliasing (free). Optional bf16 copy out.
// ---------------------------------------------------------------------------
__global__ __launch_bounds__(256) void gemm_nt(const float* __restrict__ A,
                                               const float* __restrict__ W,
                                               float* __restrict__ C,
                                               unsigned short* __restrict__ Cbf) {
    __shared__ float As[8][132];
    __shared__ float Bs[8][132];
    const int tid  = threadIdx.x;
    const int row0 = blockIdx.x * 128;
    const int col0 = blockIdx.y * 128;
    const int lane = tid & 63, w = tid >> 6;
    const int lx = lane & 7, ly = lane >> 3;
    const int mywr = (w & 1) * 64 + ly * 8;   // row offset in tile
    const int mywc = (w >> 1) * 64 + lx * 8;  // col offset in tile
    const int lr = tid >> 1, lc = (tid & 1) * 4;  // staging: 128 rows x 8 cols
    const float* Ap = A + (size_t)(row0 + lr) * D_DIM + lc;
    const float* Wp = W + (size_t)(col0 + lr) * D_DIM + lc;
    float acc[8][8] = {};
    for (int k0 = 0; k0 < D_DIM; k0 += 8) {
        float4 av = *(const float4*)(Ap + k0);
        float4 wv = *(const float4*)(Wp + k0);
        __syncthreads();
        As[lc + 0][lr] = av.x; As[lc + 1][lr] = av.y;
        As[lc + 2][lr] = av.z; As[lc + 3][lr] = av.w;
        Bs[lc + 0][lr] = wv.x; Bs[lc + 1][lr] = wv.y;
        Bs[lc + 2][lr] = wv.z; Bs[lc + 3][lr] = wv.w;
        __syncthreads();
#pragma unroll
        for (int kk = 0; kk < 8; ++kk) {
            float a_[8], b_[8];
#pragma unroll
            for (int i = 0; i < 8; ++i) a_[i] = As[kk][mywr + i];
#pragma unroll
            for (int j = 0; j < 8; ++j) b_[j] = Bs[kk][mywc + j];
#pragma unroll
            for (int i = 0; i < 8; ++i)
#pragma unroll
                for (int j = 0; j < 8; ++j)
                    acc[i][j] = fmaf(a_[i], b_[j], acc[i][j]);
        }
    }
#pragma unroll
    for (int i = 0; i < 8; ++i) {
        const size_t off = (size_t)(row0 + mywr + i) * D_DIM + col0 + mywc;
        float4 v0 = {acc[i][0], acc[i][1], acc[i][2], acc[i][3]};
        float4 v1 = {acc[i][4], acc[i][5], acc[i][6], acc[i][7]};
        *(float4*)(C + off)     = v0;
        *(float4*)(C + off + 4) = v1;
        if (Cbf) {
            ushort4 b0 = {f2bf(v0.x), f2bf(v0.y), f2bf(v0.z), f2bf(v0.w)};
            ushort4 b1 = {f2bf(v1.x), f2bf(v1.y), f2bf(v1.z), f2bf(v1.w)};
            *(ushort4*)(Cbf + off)     = b0;
            *(ushort4*)(Cbf + off + 4) = b1;
        }
    }
}

// ---------------------------------------------------------------------------
// bf16 MFMA GEMM (NT): C[m,e] = sum_d A[m,d]*W[e,d], A/W bf16 row-major,
// C f32. 128x128 tile, BK=32, 4 waves (2x2), 4x4 16x16x32 frags per wave.
// global_load_lds width 16 with pre-swizzled global source; XOR-swizzled
// LDS so ds_read_b128 fragment reads spread across banks.
// ---------------------------------------------------------------------------
__global__ __launch_bounds__(256) void gemm_bf16_nt(const unsigned short* __restrict__ A,
                                                    const unsigned short* __restrict__ W,
                                                    float* __restrict__ C) {
    __shared__ unsigned short lA[128 * 32];   // 8 KB, swizzled
    __shared__ unsigned short lB[128 * 32];
    const int tid  = threadIdx.x;
    const int lane = tid & 63, wid = tid >> 6;
    const int wy = wid & 1, wx = wid >> 1;    // 2x2 wave grid
    const int fr = lane & 15, fq = lane >> 4;
    const int row0 = blockIdx.x * 128;
    const int col0 = blockIdx.y * 128;

    // staging: slot s (of 512) = LDS bytes [s*16, s*16+16).
    // layout: slot s = r*4 + sslot holds data (row r, ksub = sslot ^ (r&3)).
    const int rS   = tid >> 2;
    const int subS = (tid & 3) ^ (rS & 3);
    const unsigned short* gA = A + (size_t)(row0 + rS) * D_DIM + subS * 8;
    const unsigned short* gB = W + (size_t)(col0 + rS) * D_DIM + subS * 8;
    char* lA0 = (char*)lA + tid * 16;
    char* lB0 = (char*)lB + tid * 16;
    const size_t rowStep = (size_t)64 * D_DIM;   // slot tid+256 -> row +64, same sub

    // fragment read byte offsets (swizzled): addr(r,sub) = r*64 + (sub^(r&3))*16
    int offA[4], offB[4];
#pragma unroll
    for (int i = 0; i < 4; ++i) {
        const int ra = wy * 64 + i * 16 + fr;
        const int rb = wx * 64 + i * 16 + fr;
        offA[i] = ra * 64 + ((fq ^ (ra & 3)) << 4);
        offB[i] = rb * 64 + ((fq ^ (rb & 3)) << 4);
    }

    f32x4 acc[4][4];
#pragma unroll
    for (int i = 0; i < 4; ++i)
#pragma unroll
        for (int j = 0; j < 4; ++j) acc[i][j] = (f32x4){0.f, 0.f, 0.f, 0.f};

    for (int k0 = 0; k0 < D_DIM; k0 += 32) {
        __syncthreads();                      // prev compute done
        GLOAD16(gA + k0, lA0);
        GLOAD16(gA + k0 + rowStep, lA0 + 4096);
        GLOAD16(gB + k0, lB0);
        GLOAD16(gB + k0 + rowStep, lB0 + 4096);
        __syncthreads();                      // drains vmcnt(0) then barrier
        short8 af[4], bf[4];
#pragma unroll
        for (int i = 0; i < 4; ++i) af[i] = *(const short8*)((const char*)lA + offA[i]);
#pragma unroll
        for (int j = 0; j < 4; ++j) bf[j] = *(const short8*)((const char*)lB + offB[j]);
#pragma unroll
        for (int i = 0; i < 4; ++i)
#pragma unroll
            for (int j = 0; j < 4; ++j)
                acc[i][j] = __builtin_amdgcn_mfma_f32_16x16x32_bf16(af[i], bf[j], acc[i][j], 0, 0, 0);
    }
    // C/D layout: col = lane&15, row = (lane>>4)*4 + reg  [m89/m91 verified]
#pragma unroll
    for (int i = 0; i < 4; ++i)
#pragma unroll
        for (int j = 0; j < 4; ++j) {
            const int r0 = row0 + wy * 64 + i * 16 + fq * 4;
            const int c  = col0 + wx * 64 + j * 16 + fr;
#pragma unroll
            for (int r = 0; r < 4; ++r)
                C[(size_t)(r0 + r) * D_DIM + c] = acc[i][j][r];
        }
}

// ---------------------------------------------------------------------------
// Router p: p[l] = 0.5*(1 - cos(q[l-1], k[l]))
// ---------------------------------------------------------------------------
__global__ __launch_bounds__(256) void router_p(const float* __restrict__ q,
                                                const float* __restrict__ k,
                                                float* __restrict__ p) {
    const int l = blockIdx.x + 1;
    const float4* qr = (const float4*)(q + (size_t)(l - 1) * D_DIM);
    const float4* kr = (const float4*)(k + (size_t)l * D_DIM);
    float4 a = qr[threadIdx.x];
    float4 b = kr[threadIdx.x];
    float dot = a.x * b.x + a.y * b.y + a.z * b.z + a.w * b.w;
    float nq  = a.x * a.x + a.y * a.y + a.z * a.z + a.w * a.w;
    float nk  = b.x * b.x + b.y * b.y + b.z * b.z + b.w * b.w;
#pragma unroll
    for (int off = 32; off > 0; off >>= 1) {
        dot += __shfl_down(dot, off);
        nq  += __shfl_down(nq,  off);
        nk  += __shfl_down(nk,  off);
    }
    __shared__ float red[3][4];
    const int w = threadIdx.x >> 6;
    if ((threadIdx.x & 63) == 0) { red[0][w] = dot; red[1][w] = nq; red[2][w] = nk; }
    __syncthreads();
    if (threadIdx.x == 0) {
        dot = red[0][0] + red[0][1] + red[0][2] + red[0][3];
        nq  = red[1][0] + red[1][1] + red[1][2] + red[1][3];
        nk  = red[2][0] + red[2][1] + red[2][2] + red[2][3];
        float dn = fmaxf(sqrtf(nq), 1e-12f) * fmaxf(sqrtf(nk), 1e-12f);
        p[l] = 0.5f * (1.f - dot / dn);
    }
}

__global__ void finalize_pab(const float* __restrict__ p, const int* __restrict__ cu,
                             int nseq, float* __restrict__ a, float* __restrict__ bs,
                             int L) {
    int l = blockIdx.x * 256 + threadIdx.x;
    if (l >= L) return;
    bool start = false;
    for (int s = 0; s < nseq; ++s) start = start || (cu[s] == l);
    float pv = (l == 0) ? 1.f : p[l];
    if (start) pv = 1.f;
    bool mask = pv > 0.5f;
    float pc  = fminf(fmaxf(pv, 1e-4f), 1.f - 1e-4f);
    a[l]  = start ? 0.f : (mask ? (1.f - pc) : 1.f);
    bs[l] = mask ? pc : 0.f;
}

__global__ void conv_bf16(const float* __restrict__ src, unsigned short* __restrict__ dst,
                          int n4) {
    int i = blockIdx.x * 256 + threadIdx.x;
    if (i >= n4) return;
    float4 v = ((const float4*)src)[i];
    ushort4 o = {f2bf(v.x), f2bf(v.y), f2bf(v.z), f2bf(v.w)};
    ((ushort4*)dst)[i] = o;
}

// ---------------------------------------------------------------------------
// Scan phase A: chunk-local scan h = a*h + bs*m in place; P = prefix prod of a.
// ---------------------------------------------------------------------------
__global__ __launch_bounds__(256) void scan_local(const float* __restrict__ a,
                                                  const float* __restrict__ bs,
                                                  float* __restrict__ m,
                                                  float* __restrict__ P) {
    __shared__ float a_s[CL], b_s[CL];
    const int chunk = blockIdx.x;
    const int d     = blockIdx.y * 256 + threadIdx.x;
    const int l0    = chunk * CL;
    for (int i = threadIdx.x; i < CL; i += 256) { a_s[i] = a[l0 + i]; b_s[i] = bs[l0 + i]; }
    __syncthreads();
    if (blockIdx.y == 0 && threadIdx.x == 0) {
        float pp = 1.f;
        for (int i = 0; i < CL; ++i) { pp *= a_s[i]; P[l0 + i] = pp; }
    }
    float h = 0.f;
    float* mp = m + (size_t)l0 * D_DIM + d;
    for (int i = 0; i < CL; ++i) {
        float mv = mp[(size_t)i * D_DIM];
        h = fmaf(a_s[i], h, b_s[i] * mv);
        mp[(size_t)i * D_DIM] = h;
    }
}

__global__ void scan_carry(const float* __restrict__ y, const float* __restrict__ P,
                           float* __restrict__ carry, int nchunks) {
    const int d = blockIdx.x * 256 + threadIdx.x;
    float H = 0.f;
    for (int c = 0; c < nchunks; ++c) {
        carry[(size_t)c * D_DIM + d] = H;
        const float Ac = P[c * CL + (CL - 1)];
        const float Bc = y[((size_t)c * CL + (CL - 1)) * D_DIM + d];
        H = fmaf(Ac, H, Bc);
    }
}

// Scan phase C + fuse: ybf = bf16(y_local + P[l]*carry + res)
__global__ void fixup_fuse(const float* __restrict__ y, const float* __restrict__ P,
                           const float* __restrict__ carry, const float* __restrict__ res,
                           unsigned short* __restrict__ ybf) {
    const size_t i4  = (size_t)blockIdx.x * 256 + threadIdx.x;
    const size_t idx = i4 * 4;
    const int l  = (int)(idx >> 10);
    const int dd = (int)(idx & 1023);
    const int c  = l / CL;
    const float pl = P[l];
    float4 yv = *(const float4*)(y + idx);
    const float4 cv = *(const float4*)(carry + (size_t)c * D_DIM + dd);
    const float4 rv = *(const float4*)(res + idx);
    yv.x = fmaf(pl, cv.x, yv.x) + rv.x;
    yv.y = fmaf(pl, cv.y, yv.y) + rv.y;
    yv.z = fmaf(pl, cv.z, yv.z) + rv.z;
    yv.w = fmaf(pl, cv.w, yv.w) + rv.w;
    ushort4 o = {f2bf(yv.x), f2bf(yv.y), f2bf(yv.z), f2bf(yv.w)};
    *(ushort4*)(ybf + idx) = o;
}

// ---------------------------------------------------------------------------
extern "C" void kernel_launch(void* const* d_in, const int* in_sizes, int n_in,
                              void* d_out, int out_size, void* d_ws, size_t ws_size,
                              hipStream_t stream) {
    const float* x  = (const float*)d_in[0];
    const float* Wq = (const float*)d_in[1];
    const float* Wk = (const float*)d_in[2];
    const float* Wr = (const float*)d_in[3];
    const float* We = (const float*)d_in[4];
    const float* Wm = (const float*)d_in[5];
    const float* Wd = (const float*)d_in[6];
    const int*   cu = (const int*)d_in[7];
    const int L    = in_sizes[0] / D_DIM;      // 32768
    const int nseq = in_sizes[7] - 1;          // 4
    float* out = (float*)d_out;

    char* ws = (char*)d_ws;
    const size_t LD4 = (size_t)L * D_DIM * sizeof(float);      // 128 MiB
    // region map (proven-size footprint):
    //   ws[0       : LD4)      enc f32 -> m f32 -> y f32 (scan in place)
    //   ws[LD4     : 2*LD4)    q f32; then: enc_bf16 [LD4, LD4+64M) -> ybf16;
    //                          W{m,r,d} bf16 at [LD4+64M, ...)
    //   ws[2*LD4   : +1.2M)    p, av, bs, P, carry
    //   d_out:                 k f32 -> res f32 -> final out
    float* enc  = (float*)ws;                  // then m / y
    float* qbuf = (float*)(ws + LD4);
    unsigned short* encbf = (unsigned short*)(ws + LD4);
    unsigned short* ybf   = encbf;
    unsigned short* wmb = (unsigned short*)(ws + LD4 + LD4 / 2);
    unsigned short* wrb = wmb + (size_t)D_DIM * D_DIM;
    unsigned short* wdb = wrb + (size_t)D_DIM * D_DIM;
    float* p     = (float*)(ws + 2 * LD4);
    float* av    = p  + L;
    float* bs    = av + L;
    float* P     = bs + L;
    float* carry = P  + L;                     // [nchunks, D]
    const int nchunks = L / CL;
    float* kbuf = out;
    float* res  = out;

    dim3 gg(L / 128, D_DIM / 128);

    // 1. router chain, f32
    gemm_nt<<<gg, 256, 0, stream>>>(x, We, enc, nullptr);
    gemm_nt<<<gg, 256, 0, stream>>>(enc, Wq, qbuf, nullptr);
    gemm_nt<<<gg, 256, 0, stream>>>(enc, Wk, kbuf, nullptr);
    router_p<<<L - 1, 256, 0, stream>>>(qbuf, kbuf, p);
    finalize_pab<<<(L + 255) / 256, 256, 0, stream>>>(p, cu, nseq, av, bs, L);

    // 2. bf16 conversions (q-region is dead now)
    conv_bf16<<<(L * D_DIM / 4 + 255) / 256, 256, 0, stream>>>(enc, encbf, L * D_DIM / 4);
    conv_bf16<<<(D_DIM * D_DIM / 4 + 255) / 256, 256, 0, stream>>>(Wm, wmb, D_DIM * D_DIM / 4);
    conv_bf16<<<(D_DIM * D_DIM / 4 + 255) / 256, 256, 0, stream>>>(Wr, wrb, D_DIM * D_DIM / 4);
    conv_bf16<<<(D_DIM * D_DIM / 4 + 255) / 256, 256, 0, stream>>>(Wd, wdb, D_DIM * D_DIM / 4);

    // 3. continuous chain, bf16 MFMA
    gemm_bf16_nt<<<gg, 256, 0, stream>>>(encbf, wmb, enc);   // m (over enc f32)
    gemm_bf16_nt<<<gg, 256, 0, stream>>>(encbf, wrb, res);   // residual

    // 4. chunked scan + fuse -> bf16 (y+res)
    dim3 gsl(nchunks, D_DIM / 256);
    scan_local<<<gsl, 256, 0, stream>>>(av, bs, enc, P);
    scan_carry<<<D_DIM / 256, 256, 0, stream>>>(enc, P, carry, nchunks);
    fixup_fuse<<<(size_t)L * D_DIM / 4 / 256, 256, 0, stream>>>(enc, P, carry, res, ybf);

    // 5. decoder
    gemm_bf16_nt<<<gg, 256, 0, stream>>>(ybf, wdb, out);
}

// Round 3
// 1401.186 us; speedup vs baseline: 3.7026x; 2.1930x over previous
//
#include <hip/hip_runtime.h>
#include <math.h>

#define D_DIM 1024
#define CL 512   // scan chunk length

typedef __attribute__((ext_vector_type(8))) short short8;
typedef __attribute__((ext_vector_type(4))) float f32x4;
typedef unsigned short u16;

__device__ __forceinline__ u16 f2bf(float f) {
    unsigned int u = __float_as_uint(f);
    u += 0x7fff + ((u >> 16) & 1);          // round-to-nearest-even
    return (u16)(u >> 16);
}
__device__ __forceinline__ float bf2f(u16 h) {
    return __uint_as_float((unsigned int)h << 16);
}

#define GLOAD16(g, l) __builtin_amdgcn_global_load_lds(                      \
        (const __attribute__((address_space(1))) void*)(g),                  \
        (__attribute__((address_space(3))) void*)(l), 16, 0, 0)

// ---------------------------------------------------------------------------
// bf16 MFMA GEMM (NT): C[m,e] = sum_d A[m,d]*W[e,d]. 128x128 tile, BK=32,
// 4 waves (2x2), 4x4 16x16x32 frags/wave. global_load_lds w16, XOR-swizzle.
// Writes f32 C, or bf16 Cbf if non-null.
// ---------------------------------------------------------------------------
__global__ __launch_bounds__(256) void gemm_bf16_nt(const u16* __restrict__ A,
                                                    const u16* __restrict__ W,
                                                    float* __restrict__ C,
                                                    u16* __restrict__ Cbf) {
    __shared__ u16 lA[128 * 32];
    __shared__ u16 lB[128 * 32];
    const int tid  = threadIdx.x;
    const int lane = tid & 63, wid = tid >> 6;
    const int wy = wid & 1, wx = wid >> 1;
    const int fr = lane & 15, fq = lane >> 4;
    const int row0 = blockIdx.x * 128;
    const int col0 = blockIdx.y * 128;

    const int rS   = tid >> 2;
    const int subS = (tid & 3) ^ (rS & 3);
    const u16* gA = A + (size_t)(row0 + rS) * D_DIM + subS * 8;
    const u16* gB = W + (size_t)(col0 + rS) * D_DIM + subS * 8;
    char* lA0 = (char*)lA + tid * 16;
    char* lB0 = (char*)lB + tid * 16;
    const size_t rowStep = (size_t)64 * D_DIM;

    int offA[4], offB[4];
#pragma unroll
    for (int i = 0; i < 4; ++i) {
        const int ra = wy * 64 + i * 16 + fr;
        const int rb = wx * 64 + i * 16 + fr;
        offA[i] = ra * 64 + ((fq ^ (ra & 3)) << 4);
        offB[i] = rb * 64 + ((fq ^ (rb & 3)) << 4);
    }

    f32x4 acc[4][4];
#pragma unroll
    for (int i = 0; i < 4; ++i)
#pragma unroll
        for (int j = 0; j < 4; ++j) acc[i][j] = (f32x4){0.f, 0.f, 0.f, 0.f};

    for (int k0 = 0; k0 < D_DIM; k0 += 32) {
        __syncthreads();
        GLOAD16(gA + k0, lA0);
        GLOAD16(gA + k0 + rowStep, lA0 + 4096);
        GLOAD16(gB + k0, lB0);
        GLOAD16(gB + k0 + rowStep, lB0 + 4096);
        __syncthreads();
        short8 af[4], bf[4];
#pragma unroll
        for (int i = 0; i < 4; ++i) af[i] = *(const short8*)((const char*)lA + offA[i]);
#pragma unroll
        for (int j = 0; j < 4; ++j) bf[j] = *(const short8*)((const char*)lB + offB[j]);
#pragma unroll
        for (int i = 0; i < 4; ++i)
#pragma unroll
            for (int j = 0; j < 4; ++j)
                acc[i][j] = __builtin_amdgcn_mfma_f32_16x16x32_bf16(af[i], bf[j], acc[i][j], 0, 0, 0);
    }
#pragma unroll
    for (int i = 0; i < 4; ++i)
#pragma unroll
        for (int j = 0; j < 4; ++j) {
            const int r0 = row0 + wy * 64 + i * 16 + fq * 4;
            const int c  = col0 + wx * 64 + j * 16 + fr;
            if (Cbf) {
#pragma unroll
                for (int r = 0; r < 4; ++r)
                    Cbf[(size_t)(r0 + r) * D_DIM + c] = f2bf(acc[i][j][r]);
            } else {
#pragma unroll
                for (int r = 0; r < 4; ++r)
                    C[(size_t)(r0 + r) * D_DIM + c] = acc[i][j][r];
            }
        }
}

// ---------------------------------------------------------------------------
// bf16x3 split-precision GEMM (NT): C = (Ah+Al)@(Wh+Wl)^T minus lo*lo term.
// Same structure, 4 LDS tiles, 3 MFMAs per fragment pair. f32 out.
// ---------------------------------------------------------------------------
__global__ __launch_bounds__(256) void gemm_bf16x3_nt(const u16* __restrict__ Ah,
                                                      const u16* __restrict__ Al,
                                                      const u16* __restrict__ Wh,
                                                      const u16* __restrict__ Wl,
                                                      float* __restrict__ C) {
    __shared__ u16 lAh[128 * 32], lAl[128 * 32];
    __shared__ u16 lBh[128 * 32], lBl[128 * 32];
    const int tid  = threadIdx.x;
    const int lane = tid & 63, wid = tid >> 6;
    const int wy = wid & 1, wx = wid >> 1;
    const int fr = lane & 15, fq = lane >> 4;
    const int row0 = blockIdx.x * 128;
    const int col0 = blockIdx.y * 128;

    const int rS   = tid >> 2;
    const int subS = (tid & 3) ^ (rS & 3);
    const size_t gOffA = (size_t)(row0 + rS) * D_DIM + subS * 8;
    const size_t gOffB = (size_t)(col0 + rS) * D_DIM + subS * 8;
    const size_t rowStep = (size_t)64 * D_DIM;
    char* sAh = (char*)lAh + tid * 16;
    char* sAl = (char*)lAl + tid * 16;
    char* sBh = (char*)lBh + tid * 16;
    char* sBl = (char*)lBl + tid * 16;

    int offA[4], offB[4];
#pragma unroll
    for (int i = 0; i < 4; ++i) {
        const int ra = wy * 64 + i * 16 + fr;
        const int rb = wx * 64 + i * 16 + fr;
        offA[i] = ra * 64 + ((fq ^ (ra & 3)) << 4);
        offB[i] = rb * 64 + ((fq ^ (rb & 3)) << 4);
    }

    f32x4 acc[4][4];
#pragma unroll
    for (int i = 0; i < 4; ++i)
#pragma unroll
        for (int j = 0; j < 4; ++j) acc[i][j] = (f32x4){0.f, 0.f, 0.f, 0.f};

    for (int k0 = 0; k0 < D_DIM; k0 += 32) {
        __syncthreads();
        GLOAD16(Ah + gOffA + k0, sAh);
        GLOAD16(Ah + gOffA + k0 + rowStep, sAh + 4096);
        GLOAD16(Al + gOffA + k0, sAl);
        GLOAD16(Al + gOffA + k0 + rowStep, sAl + 4096);
        GLOAD16(Wh + gOffB + k0, sBh);
        GLOAD16(Wh + gOffB + k0 + rowStep, sBh + 4096);
        GLOAD16(Wl + gOffB + k0, sBl);
        GLOAD16(Wl + gOffB + k0 + rowStep, sBl + 4096);
        __syncthreads();
        short8 afh[4], afl[4], bfh[4], bfl[4];
#pragma unroll
        for (int i = 0; i < 4; ++i) {
            afh[i] = *(const short8*)((const char*)lAh + offA[i]);
            afl[i] = *(const short8*)((const char*)lAl + offA[i]);
        }
#pragma unroll
        for (int j = 0; j < 4; ++j) {
            bfh[j] = *(const short8*)((const char*)lBh + offB[j]);
            bfl[j] = *(const short8*)((const char*)lBl + offB[j]);
        }
#pragma unroll
        for (int i = 0; i < 4; ++i)
#pragma unroll
            for (int j = 0; j < 4; ++j) {
                acc[i][j] = __builtin_amdgcn_mfma_f32_16x16x32_bf16(afh[i], bfh[j], acc[i][j], 0, 0, 0);
                acc[i][j] = __builtin_amdgcn_mfma_f32_16x16x32_bf16(afh[i], bfl[j], acc[i][j], 0, 0, 0);
                acc[i][j] = __builtin_amdgcn_mfma_f32_16x16x32_bf16(afl[i], bfh[j], acc[i][j], 0, 0, 0);
            }
    }
#pragma unroll
    for (int i = 0; i < 4; ++i)
#pragma unroll
        for (int j = 0; j < 4; ++j) {
            const int r0 = row0 + wy * 64 + i * 16 + fq * 4;
            const int c  = col0 + wx * 64 + j * 16 + fr;
#pragma unroll
            for (int r = 0; r < 4; ++r)
                C[(size_t)(r0 + r) * D_DIM + c] = acc[i][j][r];
        }
}

// ---------------------------------------------------------------------------
// split f32 -> (hi, lo) bf16 pair
// ---------------------------------------------------------------------------
__global__ void split_bf16(const float* __restrict__ src, u16* __restrict__ hi,
                           u16* __restrict__ lo, int n4) {
    int i = blockIdx.x * 256 + threadIdx.x;
    if (i >= n4) return;
    float4 v = ((const float4*)src)[i];
    ushort4 h, l;
    h.x = f2bf(v.x); l.x = f2bf(v.x - bf2f(h.x));
    h.y = f2bf(v.y); l.y = f2bf(v.y - bf2f(h.y));
    h.z = f2bf(v.z); l.z = f2bf(v.z - bf2f(h.z));
    h.w = f2bf(v.w); l.w = f2bf(v.w - bf2f(h.w));
    ((ushort4*)hi)[i] = h;
    ((ushort4*)lo)[i] = l;
}

__global__ void conv_bf16(const float* __restrict__ src, u16* __restrict__ dst, int n4) {
    int i = blockIdx.x * 256 + threadIdx.x;
    if (i >= n4) return;
    float4 v = ((const float4*)src)[i];
    ushort4 o = {f2bf(v.x), f2bf(v.y), f2bf(v.z), f2bf(v.w)};
    ((ushort4*)dst)[i] = o;
}

// transpose + split: T[d,e] = W[e,d] as (hi,lo) bf16
__global__ __launch_bounds__(256) void transpose_split(const float* __restrict__ W,
                                                       u16* __restrict__ Th,
                                                       u16* __restrict__ Tl) {
    __shared__ float tile[32][33];
    const int e0 = blockIdx.x * 32, d0 = blockIdx.y * 32;
    const int tx = threadIdx.x & 31, ty = threadIdx.x >> 5;
#pragma unroll
    for (int i = 0; i < 32; i += 8)
        tile[ty + i][tx] = W[(size_t)(e0 + ty + i) * D_DIM + d0 + tx];
    __syncthreads();
#pragma unroll
    for (int i = 0; i < 32; i += 8) {
        float v = tile[tx][ty + i];
        u16 h = f2bf(v);
        Th[(size_t)(d0 + ty + i) * D_DIM + e0 + tx] = h;
        Tl[(size_t)(d0 + ty + i) * D_DIM + e0 + tx] = f2bf(v - bf2f(h));
    }
}

// ---------------------------------------------------------------------------
// row sum of squares (bf16 rows)
// ---------------------------------------------------------------------------
__global__ __launch_bounds__(256) void rowsumsq(const u16* __restrict__ q,
                                                float* __restrict__ nrm) {
    const int l = blockIdx.x;
    ushort4 v = ((const ushort4*)(q + (size_t)l * D_DIM))[threadIdx.x];
    float a = bf2f(v.x), b = bf2f(v.y), c = bf2f(v.z), d = bf2f(v.w);
    float s = a * a + b * b + c * c + d * d;
#pragma unroll
    for (int off = 32; off > 0; off >>= 1) s += __shfl_down(s, off);
    __shared__ float red[4];
    const int w = threadIdx.x >> 6;
    if ((threadIdx.x & 63) == 0) red[w] = s;
    __syncthreads();
    if (threadIdx.x == 0) nrm[l] = red[0] + red[1] + red[2] + red[3];
}

// ---------------------------------------------------------------------------
// router: p[l] = 0.5*(1 - dot/(|q[l-1]||k[l]|)), dot = (ench+encl)[l-1] . t[l]
// ---------------------------------------------------------------------------
__global__ __launch_bounds__(256) void router_p2(const u16* __restrict__ ench,
                                                 const u16* __restrict__ encl,
                                                 const float* __restrict__ t,
                                                 const float* __restrict__ nq,
                                                 const float* __restrict__ nk,
                                                 float* __restrict__ p) {
    const int l = blockIdx.x + 1;
    ushort4 h  = ((const ushort4*)(ench + (size_t)(l - 1) * D_DIM))[threadIdx.x];
    ushort4 lo = ((const ushort4*)(encl + (size_t)(l - 1) * D_DIM))[threadIdx.x];
    float4  tv = ((const float4*)(t + (size_t)l * D_DIM))[threadIdx.x];
    float dot = (bf2f(h.x) + bf2f(lo.x)) * tv.x
              + (bf2f(h.y) + bf2f(lo.y)) * tv.y
              + (bf2f(h.z) + bf2f(lo.z)) * tv.z
              + (bf2f(h.w) + bf2f(lo.w)) * tv.w;
#pragma unroll
    for (int off = 32; off > 0; off >>= 1) dot += __shfl_down(dot, off);
    __shared__ float red[4];
    const int w = threadIdx.x >> 6;
    if ((threadIdx.x & 63) == 0) red[w] = dot;
    __syncthreads();
    if (threadIdx.x == 0) {
        dot = red[0] + red[1] + red[2] + red[3];
        float dn = fmaxf(sqrtf(nq[l - 1]), 1e-12f) * fmaxf(sqrtf(nk[l]), 1e-12f);
        p[l] = 0.5f * (1.f - dot / dn);
    }
}

__global__ void finalize_pab(const float* __restrict__ p, const int* __restrict__ cu,
                             int nseq, float* __restrict__ a, float* __restrict__ bs,
                             int L) {
    int l = blockIdx.x * 256 + threadIdx.x;
    if (l >= L) return;
    bool start = false;
    for (int s = 0; s < nseq; ++s) start = start || (cu[s] == l);
    float pv = (l == 0) ? 1.f : p[l];
    if (start) pv = 1.f;
    bool mask = pv > 0.5f;
    float pc  = fminf(fmaxf(pv, 1e-4f), 1.f - 1e-4f);
    a[l]  = start ? 0.f : (mask ? (1.f - pc) : 1.f);
    bs[l] = mask ? pc : 0.f;
}

// ---------------------------------------------------------------------------
// scan kernels (unchanged, f32)
// ---------------------------------------------------------------------------
__global__ __launch_bounds__(256) void scan_local(const float* __restrict__ a,
                                                  const float* __restrict__ bs,
                                                  float* __restrict__ m,
                                                  float* __restrict__ P) {
    __shared__ float a_s[CL], b_s[CL];
    const int chunk = blockIdx.x;
    const int d     = blockIdx.y * 256 + threadIdx.x;
    const int l0    = chunk * CL;
    for (int i = threadIdx.x; i < CL; i += 256) { a_s[i] = a[l0 + i]; b_s[i] = bs[l0 + i]; }
    __syncthreads();
    if (blockIdx.y == 0 && threadIdx.x == 0) {
        float pp = 1.f;
        for (int i = 0; i < CL; ++i) { pp *= a_s[i]; P[l0 + i] = pp; }
    }
    float h = 0.f;
    float* mp = m + (size_t)l0 * D_DIM + d;
    for (int i = 0; i < CL; ++i) {
        float mv = mp[(size_t)i * D_DIM];
        h = fmaf(a_s[i], h, b_s[i] * mv);
        mp[(size_t)i * D_DIM] = h;
    }
}

__global__ void scan_carry(const float* __restrict__ y, const float* __restrict__ P,
                           float* __restrict__ carry, int nchunks) {
    const int d = blockIdx.x * 256 + threadIdx.x;
    float H = 0.f;
    for (int c = 0; c < nchunks; ++c) {
        carry[(size_t)c * D_DIM + d] = H;
        const float Ac = P[c * CL + (CL - 1)];
        const float Bc = y[((size_t)c * CL + (CL - 1)) * D_DIM + d];
        H = fmaf(Ac, H, Bc);
    }
}

__global__ void fixup_fuse(const float* __restrict__ y, const float* __restrict__ P,
                           const float* __restrict__ carry, const float* __restrict__ res,
                           u16* __restrict__ ybf) {
    const size_t i4  = (size_t)blockIdx.x * 256 + threadIdx.x;
    const size_t idx = i4 * 4;
    const int l  = (int)(idx >> 10);
    const int dd = (int)(idx & 1023);
    const int c  = l / CL;
    const float pl = P[l];
    float4 yv = *(const float4*)(y + idx);
    const float4 cv = *(const float4*)(carry + (size_t)c * D_DIM + dd);
    const float4 rv = *(const float4*)(res + idx);
    yv.x = fmaf(pl, cv.x, yv.x) + rv.x;
    yv.y = fmaf(pl, cv.y, yv.y) + rv.y;
    yv.z = fmaf(pl, cv.z, yv.z) + rv.z;
    yv.w = fmaf(pl, cv.w, yv.w) + rv.w;
    ushort4 o = {f2bf(yv.x), f2bf(yv.y), f2bf(yv.z), f2bf(yv.w)};
    *(ushort4*)(ybf + idx) = o;
}

// ---------------------------------------------------------------------------
extern "C" void kernel_launch(void* const* d_in, const int* in_sizes, int n_in,
                              void* d_out, int out_size, void* d_ws, size_t ws_size,
                              hipStream_t stream) {
    const float* x  = (const float*)d_in[0];
    const float* Wq = (const float*)d_in[1];
    const float* Wk = (const float*)d_in[2];
    const float* Wr = (const float*)d_in[3];
    const float* We = (const float*)d_in[4];
    const float* Wm = (const float*)d_in[5];
    const float* Wd = (const float*)d_in[6];
    const int*   cu = (const int*)d_in[7];
    const int L    = in_sizes[0] / D_DIM;      // 32768
    const int nseq = in_sizes[7] - 1;          // 4

    const size_t LD2 = (size_t)L * D_DIM * 2;  // 64 MiB (bf16 plane)
    const size_t DD  = (size_t)D_DIM * D_DIM;  // 1 M elements
    const int nLD4 = L * D_DIM / 4;
    const int nDD4 = (int)(DD / 4);
    const int nchunks = L / CL;

    // ws layout (== round-2 footprint, 269.2 MB):
    //   A [0,64M):    x_hi -> enc_hi -> ybf
    //   B [64M,128M): x_lo -> enc_lo -> {Wmb,Wrb,Wdb} (after router)
    //   C [128M,256M): enc f32 -> t f32 -> m/y f32
    //   scalars at 256M: p, av, bs, P, carry
    char* ws = (char*)d_ws;
    u16*   A    = (u16*)ws;
    u16*   B    = (u16*)(ws + LD2);
    float* C    = (float*)(ws + 2 * LD2);
    float* p    = (float*)(ws + 2 * LD2 + (size_t)L * D_DIM * 4);
    float* av   = p  + L;
    float* bs   = av + L;
    float* P    = bs + L;
    float* carry= P  + L;
    u16* Wmb = B;                 // placed in B after enc_lo is dead
    u16* Wrb = B + DD;
    u16* Wdb = B + 2 * DD;

    // d_out transient layout (all dead before res overwrites d_out):
    char* dob = (char*)d_out;
    u16* Weh  = (u16*)dob;                    //  0- 2M
    u16* Wel  = (u16*)(dob + (2u << 20));     //  2- 4M
    u16* WqTh = (u16*)(dob + (4u << 20));
    u16* WqTl = (u16*)(dob + (6u << 20));
    u16* WkTh = (u16*)(dob + (8u << 20));
    u16* WkTl = (u16*)(dob + (10u << 20));
    float* Mf = (float*)(dob + (12u << 20));  // 12-16M f32
    u16* Mh   = (u16*)(dob + (16u << 20));
    u16* Ml   = (u16*)(dob + (18u << 20));
    u16* qkbf = (u16*)dob;                    // 0-64M (after t-GEMM)
    u16* Wqb  = (u16*)(dob + (64u << 20));
    u16* Wkb  = (u16*)(dob + (66u << 20));
    float* nq = (float*)(dob + (68u << 20));
    float* nk = nq + L;
    float* out = (float*)d_out;

    dim3 gL(L / 128, D_DIM / 128);            // (256, 8)
    dim3 gD(D_DIM / 128, D_DIM / 128);        // (8, 8)
    dim3 gT(D_DIM / 32, D_DIM / 32);          // (32, 32)

    // 1. splits of x and We
    split_bf16<<<(nLD4 + 255) / 256, 256, 0, stream>>>(x, A, B, nLD4);
    split_bf16<<<(nDD4 + 255) / 256, 256, 0, stream>>>(We, Weh, Wel, nDD4);
    // 2. enc = x @ We^T  (bf16x3, f32 out -> C)
    gemm_bf16x3_nt<<<gL, 256, 0, stream>>>(A, B, Weh, Wel, C);
    // 3. split enc -> (A=enc_hi, B=enc_lo)
    split_bf16<<<(nLD4 + 255) / 256, 256, 0, stream>>>(C, A, B, nLD4);
    // 4. M = Wq^T @ Wk via transposed splits (bf16x3)
    transpose_split<<<gT, 256, 0, stream>>>(Wq, WqTh, WqTl);
    transpose_split<<<gT, 256, 0, stream>>>(Wk, WkTh, WkTl);
    gemm_bf16x3_nt<<<gD, 256, 0, stream>>>(WqTh, WqTl, WkTh, WkTl, Mf);
    split_bf16<<<(nDD4 + 255) / 256, 256, 0, stream>>>(Mf, Mh, Ml, nDD4);
    // 5. t = enc @ M^T (bf16x3) -> C (enc f32 dead)
    gemm_bf16x3_nt<<<gL, 256, 0, stream>>>(A, B, Mh, Ml, C);
    // 6. q,k norms (plain bf16, serial reuse of d_out[0:64M))
    conv_bf16<<<(nDD4 + 255) / 256, 256, 0, stream>>>(Wq, Wqb, nDD4);
    conv_bf16<<<(nDD4 + 255) / 256, 256, 0, stream>>>(Wk, Wkb, nDD4);
    gemm_bf16_nt<<<gL, 256, 0, stream>>>(A, Wqb, nullptr, qkbf);
    rowsumsq<<<L, 256, 0, stream>>>(qkbf, nq);
    gemm_bf16_nt<<<gL, 256, 0, stream>>>(A, Wkb, nullptr, qkbf);
    rowsumsq<<<L, 256, 0, stream>>>(qkbf, nk);
    // 7. router + gates
    router_p2<<<L - 1, 256, 0, stream>>>(A, B, C, nq, nk, p);
    finalize_pab<<<(L + 255) / 256, 256, 0, stream>>>(p, cu, nseq, av, bs, L);
    // 8. weights for continuous chain into B (enc_lo dead now)
    conv_bf16<<<(nDD4 + 255) / 256, 256, 0, stream>>>(Wm, Wmb, nDD4);
    conv_bf16<<<(nDD4 + 255) / 256, 256, 0, stream>>>(Wr, Wrb, nDD4);
    conv_bf16<<<(nDD4 + 255) / 256, 256, 0, stream>>>(Wd, Wdb, nDD4);
    // 9. m = enc @ Wm^T -> C (t dead); res = enc @ Wr^T -> d_out
    gemm_bf16_nt<<<gL, 256, 0, stream>>>(A, Wmb, C, nullptr);
    gemm_bf16_nt<<<gL, 256, 0, stream>>>(A, Wrb, out, nullptr);
    // 10. chunked scan over m (in place) + fuse residual -> ybf (A, enc_hi dead)
    dim3 gsl(nchunks, D_DIM / 256);
    scan_local<<<gsl, 256, 0, stream>>>(av, bs, C, P);
    scan_carry<<<D_DIM / 256, 256, 0, stream>>>(C, P, carry, nchunks);
    fixup_fuse<<<(size_t)L * D_DIM / 4 / 256, 256, 0, stream>>>(C, P, carry, out, A);
    // 11. decoder
    gemm_bf16_nt<<<gL, 256, 0, stream>>>(A, Wdb, out, nullptr);
}

// Round 4
// 1200.407 us; speedup vs baseline: 4.3219x; 1.1673x over previous
//
#include <hip/hip_runtime.h>
#include <math.h>

#define D_DIM 1024
#define CL 512   // scan chunk length

typedef __attribute__((ext_vector_type(8))) short short8;
typedef __attribute__((ext_vector_type(4))) float f32x4;
typedef unsigned short u16;

__device__ __forceinline__ u16 f2bf(float f) {
    unsigned int u = __float_as_uint(f);
    u += 0x7fff + ((u >> 16) & 1);          // round-to-nearest-even
    return (u16)(u >> 16);
}
__device__ __forceinline__ float bf2f(u16 h) {
    return __uint_as_float((unsigned int)h << 16);
}

#define GLOAD16(g, l) __builtin_amdgcn_global_load_lds(                      \
        (const __attribute__((address_space(1))) void*)(g),                  \
        (__attribute__((address_space(3))) void*)(l), 16, 0, 0)

// Swizzle (2-way, free): data (row r, ksub s) lives at LDS byte
//   r*64 + (s ^ ((r>>1)&3))*16.  Bank base = 16(r&1) + 4(s^((r>>1)&3)):
// 16 lanes reading consecutive rows at fixed s hit 8 distinct 4-bank bases.

// ---------------------------------------------------------------------------
// plain bf16 MFMA GEMM (NT): C = A@W^T. 128x128 tile, BK=32, 4 waves.
// f32 C or bf16 Cbf (whichever non-null).
// ---------------------------------------------------------------------------
__global__ __launch_bounds__(256) void gemm_bf16_nt(const u16* __restrict__ A,
                                                    const u16* __restrict__ W,
                                                    float* __restrict__ C,
                                                    u16* __restrict__ Cbf) {
    __shared__ u16 lA[128 * 32];
    __shared__ u16 lB[128 * 32];
    const int tid  = threadIdx.x;
    const int lane = tid & 63, wid = tid >> 6;
    const int wy = wid & 1, wx = wid >> 1;
    const int fr = lane & 15, fq = lane >> 4;
    const int row0 = blockIdx.x * 128;
    const int col0 = blockIdx.y * 128;

    const int rS   = tid >> 2;
    const int subS = (tid & 3) ^ ((rS >> 1) & 3);
    const u16* gA = A + (size_t)(row0 + rS) * D_DIM + subS * 8;
    const u16* gB = W + (size_t)(col0 + rS) * D_DIM + subS * 8;
    char* lA0 = (char*)lA + tid * 16;
    char* lB0 = (char*)lB + tid * 16;
    const size_t rowStep = (size_t)64 * D_DIM;

    int offA[4], offB[4];
#pragma unroll
    for (int i = 0; i < 4; ++i) {
        const int ra = wy * 64 + i * 16 + fr;
        const int rb = wx * 64 + i * 16 + fr;
        offA[i] = ra * 64 + ((fq ^ ((ra >> 1) & 3)) << 4);
        offB[i] = rb * 64 + ((fq ^ ((rb >> 1) & 3)) << 4);
    }

    f32x4 acc[4][4];
#pragma unroll
    for (int i = 0; i < 4; ++i)
#pragma unroll
        for (int j = 0; j < 4; ++j) acc[i][j] = (f32x4){0.f, 0.f, 0.f, 0.f};

    for (int k0 = 0; k0 < D_DIM; k0 += 32) {
        __syncthreads();
        GLOAD16(gA + k0, lA0);
        GLOAD16(gA + k0 + rowStep, lA0 + 4096);
        GLOAD16(gB + k0, lB0);
        GLOAD16(gB + k0 + rowStep, lB0 + 4096);
        __syncthreads();
        short8 af[4], bf[4];
#pragma unroll
        for (int i = 0; i < 4; ++i) af[i] = *(const short8*)((const char*)lA + offA[i]);
#pragma unroll
        for (int j = 0; j < 4; ++j) bf[j] = *(const short8*)((const char*)lB + offB[j]);
#pragma unroll
        for (int i = 0; i < 4; ++i)
#pragma unroll
            for (int j = 0; j < 4; ++j)
                acc[i][j] = __builtin_amdgcn_mfma_f32_16x16x32_bf16(af[i], bf[j], acc[i][j], 0, 0, 0);
    }
#pragma unroll
    for (int i = 0; i < 4; ++i)
#pragma unroll
        for (int j = 0; j < 4; ++j) {
            const int r0 = row0 + wy * 64 + i * 16 + fq * 4;
            const int c  = col0 + wx * 64 + j * 16 + fr;
            if (Cbf) {
#pragma unroll
                for (int r = 0; r < 4; ++r)
                    Cbf[(size_t)(r0 + r) * D_DIM + c] = f2bf(acc[i][j][r]);
            } else {
#pragma unroll
                for (int r = 0; r < 4; ++r)
                    C[(size_t)(r0 + r) * D_DIM + c] = acc[i][j][r];
            }
        }
}

// ---------------------------------------------------------------------------
// norm-only GEMM: computes A@W^T but only emits per-row sum of squares over
// this block's 128-col slice -> part[blockIdx.y * M + row]. No C traffic.
// ---------------------------------------------------------------------------
__global__ __launch_bounds__(256) void gemm_norm(const u16* __restrict__ A,
                                                 const u16* __restrict__ W,
                                                 float* __restrict__ part) {
    __shared__ u16 lA[128 * 32];
    __shared__ u16 lB[128 * 32];
    const int tid  = threadIdx.x;
    const int lane = tid & 63, wid = tid >> 6;
    const int wy = wid & 1, wx = wid >> 1;
    const int fr = lane & 15, fq = lane >> 4;
    const int row0 = blockIdx.x * 128;
    const int col0 = blockIdx.y * 128;

    const int rS   = tid >> 2;
    const int subS = (tid & 3) ^ ((rS >> 1) & 3);
    const u16* gA = A + (size_t)(row0 + rS) * D_DIM + subS * 8;
    const u16* gB = W + (size_t)(col0 + rS) * D_DIM + subS * 8;
    char* lA0 = (char*)lA + tid * 16;
    char* lB0 = (char*)lB + tid * 16;
    const size_t rowStep = (size_t)64 * D_DIM;

    int offA[4], offB[4];
#pragma unroll
    for (int i = 0; i < 4; ++i) {
        const int ra = wy * 64 + i * 16 + fr;
        const int rb = wx * 64 + i * 16 + fr;
        offA[i] = ra * 64 + ((fq ^ ((ra >> 1) & 3)) << 4);
        offB[i] = rb * 64 + ((fq ^ ((rb >> 1) & 3)) << 4);
    }

    f32x4 acc[4][4];
#pragma unroll
    for (int i = 0; i < 4; ++i)
#pragma unroll
        for (int j = 0; j < 4; ++j) acc[i][j] = (f32x4){0.f, 0.f, 0.f, 0.f};

    for (int k0 = 0; k0 < D_DIM; k0 += 32) {
        __syncthreads();
        GLOAD16(gA + k0, lA0);
        GLOAD16(gA + k0 + rowStep, lA0 + 4096);
        GLOAD16(gB + k0, lB0);
        GLOAD16(gB + k0 + rowStep, lB0 + 4096);
        __syncthreads();
        short8 af[4], bf[4];
#pragma unroll
        for (int i = 0; i < 4; ++i) af[i] = *(const short8*)((const char*)lA + offA[i]);
#pragma unroll
        for (int j = 0; j < 4; ++j) bf[j] = *(const short8*)((const char*)lB + offB[j]);
#pragma unroll
        for (int i = 0; i < 4; ++i)
#pragma unroll
            for (int j = 0; j < 4; ++j)
                acc[i][j] = __builtin_amdgcn_mfma_f32_16x16x32_bf16(af[i], bf[j], acc[i][j], 0, 0, 0);
    }
    // per-row sum of squares over this wave's 64 cols
    __shared__ float rowsum[2][128];
#pragma unroll
    for (int i = 0; i < 4; ++i)
#pragma unroll
        for (int r = 0; r < 4; ++r) {
            float s = acc[i][0][r] * acc[i][0][r] + acc[i][1][r] * acc[i][1][r]
                    + acc[i][2][r] * acc[i][2][r] + acc[i][3][r] * acc[i][3][r];
#pragma unroll
            for (int off = 1; off < 16; off <<= 1) s += __shfl_xor(s, off);
            if (fr == 0) rowsum[wx][wy * 64 + i * 16 + fq * 4 + r] = s;
        }
    __syncthreads();
    if (tid < 128)
        part[(size_t)blockIdx.y * (gridDim.x * 128) + row0 + tid] =
            rowsum[0][tid] + rowsum[1][tid];
}

// ---------------------------------------------------------------------------
// bf16x3 split-precision GEMM: C = Ah@Wh^T + Ah@Wl^T + Al@Wh^T.
// Output: f32 C, or (Chi,Clo) bf16 split planes.
// ---------------------------------------------------------------------------
__global__ __launch_bounds__(256) void gemm_bf16x3_nt(const u16* __restrict__ Ah,
                                                      const u16* __restrict__ Al,
                                                      const u16* __restrict__ Wh,
                                                      const u16* __restrict__ Wl,
                                                      float* __restrict__ C,
                                                      u16* __restrict__ Chi,
                                                      u16* __restrict__ Clo) {
    __shared__ u16 lAh[128 * 32], lAl[128 * 32];
    __shared__ u16 lBh[128 * 32], lBl[128 * 32];
    const int tid  = threadIdx.x;
    const int lane = tid & 63, wid = tid >> 6;
    const int wy = wid & 1, wx = wid >> 1;
    const int fr = lane & 15, fq = lane >> 4;
    const int row0 = blockIdx.x * 128;
    const int col0 = blockIdx.y * 128;

    const int rS   = tid >> 2;
    const int subS = (tid & 3) ^ ((rS >> 1) & 3);
    const size_t gOffA = (size_t)(row0 + rS) * D_DIM + subS * 8;
    const size_t gOffB = (size_t)(col0 + rS) * D_DIM + subS * 8;
    const size_t rowStep = (size_t)64 * D_DIM;
    char* sAh = (char*)lAh + tid * 16;
    char* sAl = (char*)lAl + tid * 16;
    char* sBh = (char*)lBh + tid * 16;
    char* sBl = (char*)lBl + tid * 16;

    int offA[4], offB[4];
#pragma unroll
    for (int i = 0; i < 4; ++i) {
        const int ra = wy * 64 + i * 16 + fr;
        const int rb = wx * 64 + i * 16 + fr;
        offA[i] = ra * 64 + ((fq ^ ((ra >> 1) & 3)) << 4);
        offB[i] = rb * 64 + ((fq ^ ((rb >> 1) & 3)) << 4);
    }

    f32x4 acc[4][4];
#pragma unroll
    for (int i = 0; i < 4; ++i)
#pragma unroll
        for (int j = 0; j < 4; ++j) acc[i][j] = (f32x4){0.f, 0.f, 0.f, 0.f};

    for (int k0 = 0; k0 < D_DIM; k0 += 32) {
        __syncthreads();
        GLOAD16(Ah + gOffA + k0, sAh);
        GLOAD16(Ah + gOffA + k0 + rowStep, sAh + 4096);
        GLOAD16(Al + gOffA + k0, sAl);
        GLOAD16(Al + gOffA + k0 + rowStep, sAl + 4096);
        GLOAD16(Wh + gOffB + k0, sBh);
        GLOAD16(Wh + gOffB + k0 + rowStep, sBh + 4096);
        GLOAD16(Wl + gOffB + k0, sBl);
        GLOAD16(Wl + gOffB + k0 + rowStep, sBl + 4096);
        __syncthreads();
        short8 afh[4], afl[4], bfh[4], bfl[4];
#pragma unroll
        for (int i = 0; i < 4; ++i) {
            afh[i] = *(const short8*)((const char*)lAh + offA[i]);
            afl[i] = *(const short8*)((const char*)lAl + offA[i]);
        }
#pragma unroll
        for (int j = 0; j < 4; ++j) {
            bfh[j] = *(const short8*)((const char*)lBh + offB[j]);
            bfl[j] = *(const short8*)((const char*)lBl + offB[j]);
        }
#pragma unroll
        for (int i = 0; i < 4; ++i)
#pragma unroll
            for (int j = 0; j < 4; ++j) {
                acc[i][j] = __builtin_amdgcn_mfma_f32_16x16x32_bf16(afh[i], bfh[j], acc[i][j], 0, 0, 0);
                acc[i][j] = __builtin_amdgcn_mfma_f32_16x16x32_bf16(afh[i], bfl[j], acc[i][j], 0, 0, 0);
                acc[i][j] = __builtin_amdgcn_mfma_f32_16x16x32_bf16(afl[i], bfh[j], acc[i][j], 0, 0, 0);
            }
    }
#pragma unroll
    for (int i = 0; i < 4; ++i)
#pragma unroll
        for (int j = 0; j < 4; ++j) {
            const int r0 = row0 + wy * 64 + i * 16 + fq * 4;
            const int c  = col0 + wx * 64 + j * 16 + fr;
            if (Chi) {
#pragma unroll
                for (int r = 0; r < 4; ++r) {
                    const float v = acc[i][j][r];
                    const u16 h  = f2bf(v);
                    Chi[(size_t)(r0 + r) * D_DIM + c] = h;
                    Clo[(size_t)(r0 + r) * D_DIM + c] = f2bf(v - bf2f(h));
                }
            } else {
#pragma unroll
                for (int r = 0; r < 4; ++r)
                    C[(size_t)(r0 + r) * D_DIM + c] = acc[i][j][r];
            }
        }
}

// ---------------------------------------------------------------------------
// fused decoder GEMM: out = A1@W1^T + A2@W2^T (K = 2*1024), f32 out.
// ---------------------------------------------------------------------------
__global__ __launch_bounds__(256) void gemm_dec2(const u16* __restrict__ A1,
                                                 const u16* __restrict__ A2,
                                                 const u16* __restrict__ W1,
                                                 const u16* __restrict__ W2,
                                                 float* __restrict__ C) {
    __shared__ u16 lA[128 * 32];
    __shared__ u16 lB[128 * 32];
    const int tid  = threadIdx.x;
    const int lane = tid & 63, wid = tid >> 6;
    const int wy = wid & 1, wx = wid >> 1;
    const int fr = lane & 15, fq = lane >> 4;
    const int row0 = blockIdx.x * 128;
    const int col0 = blockIdx.y * 128;

    const int rS   = tid >> 2;
    const int subS = (tid & 3) ^ ((rS >> 1) & 3);
    const size_t gOffA = (size_t)(row0 + rS) * D_DIM + subS * 8;
    const size_t gOffB = (size_t)(col0 + rS) * D_DIM + subS * 8;
    char* lA0 = (char*)lA + tid * 16;
    char* lB0 = (char*)lB + tid * 16;
    const size_t rowStep = (size_t)64 * D_DIM;

    int offA[4], offB[4];
#pragma unroll
    for (int i = 0; i < 4; ++i) {
        const int ra = wy * 64 + i * 16 + fr;
        const int rb = wx * 64 + i * 16 + fr;
        offA[i] = ra * 64 + ((fq ^ ((ra >> 1) & 3)) << 4);
        offB[i] = rb * 64 + ((fq ^ ((rb >> 1) & 3)) << 4);
    }

    f32x4 acc[4][4];
#pragma unroll
    for (int i = 0; i < 4; ++i)
#pragma unroll
        for (int j = 0; j < 4; ++j) acc[i][j] = (f32x4){0.f, 0.f, 0.f, 0.f};

    for (int k0 = 0; k0 < 2 * D_DIM; k0 += 32) {
        const u16* sA = (k0 < D_DIM) ? A1 : A2;
        const u16* sW = (k0 < D_DIM) ? W1 : W2;
        const int kk = k0 & (D_DIM - 1);
        __syncthreads();
        GLOAD16(sA + gOffA + kk, lA0);
        GLOAD16(sA + gOffA + kk + rowStep, lA0 + 4096);
        GLOAD16(sW + gOffB + kk, lB0);
        GLOAD16(sW + gOffB + kk + rowStep, lB0 + 4096);
        __syncthreads();
        short8 af[4], bf[4];
#pragma unroll
        for (int i = 0; i < 4; ++i) af[i] = *(const short8*)((const char*)lA + offA[i]);
#pragma unroll
        for (int j = 0; j < 4; ++j) bf[j] = *(const short8*)((const char*)lB + offB[j]);
#pragma unroll
        for (int i = 0; i < 4; ++i)
#pragma unroll
            for (int j = 0; j < 4; ++j)
                acc[i][j] = __builtin_amdgcn_mfma_f32_16x16x32_bf16(af[i], bf[j], acc[i][j], 0, 0, 0);
    }
#pragma unroll
    for (int i = 0; i < 4; ++i)
#pragma unroll
        for (int j = 0; j < 4; ++j) {
            const int r0 = row0 + wy * 64 + i * 16 + fq * 4;
            const int c  = col0 + wx * 64 + j * 16 + fr;
#pragma unroll
            for (int r = 0; r < 4; ++r)
                C[(size_t)(r0 + r) * D_DIM + c] = acc[i][j][r];
        }
}

// ---------------------------------------------------------------------------
// small kernels
// ---------------------------------------------------------------------------
__global__ void split_bf16(const float* __restrict__ src, u16* __restrict__ hi,
                           u16* __restrict__ lo, int n4) {
    int i = blockIdx.x * 256 + threadIdx.x;
    if (i >= n4) return;
    float4 v = ((const float4*)src)[i];
    ushort4 h, l;
    h.x = f2bf(v.x); l.x = f2bf(v.x - bf2f(h.x));
    h.y = f2bf(v.y); l.y = f2bf(v.y - bf2f(h.y));
    h.z = f2bf(v.z); l.z = f2bf(v.z - bf2f(h.z));
    h.w = f2bf(v.w); l.w = f2bf(v.w - bf2f(h.w));
    ((ushort4*)hi)[i] = h;
    ((ushort4*)lo)[i] = l;
}

__global__ void conv_bf16(const float* __restrict__ src, u16* __restrict__ dst, int n4) {
    int i = blockIdx.x * 256 + threadIdx.x;
    if (i >= n4) return;
    float4 v = ((const float4*)src)[i];
    ushort4 o = {f2bf(v.x), f2bf(v.y), f2bf(v.z), f2bf(v.w)};
    ((ushort4*)dst)[i] = o;
}

// transpose W -> bf16 (hi, optional lo)
__global__ __launch_bounds__(256) void transpose_split(const float* __restrict__ W,
                                                       u16* __restrict__ Th,
                                                       u16* __restrict__ Tl) {
    __shared__ float tile[32][33];
    const int e0 = blockIdx.x * 32, d0 = blockIdx.y * 32;
    const int tx = threadIdx.x & 31, ty = threadIdx.x >> 5;
#pragma unroll
    for (int i = 0; i < 32; i += 8)
        tile[ty + i][tx] = W[(size_t)(e0 + ty + i) * D_DIM + d0 + tx];
    __syncthreads();
#pragma unroll
    for (int i = 0; i < 32; i += 8) {
        float v = tile[tx][ty + i];
        u16 h = f2bf(v);
        Th[(size_t)(d0 + ty + i) * D_DIM + e0 + tx] = h;
        if (Tl) Tl[(size_t)(d0 + ty + i) * D_DIM + e0 + tx] = f2bf(v - bf2f(h));
    }
}

__global__ void combine_norm(const float* __restrict__ partq, const float* __restrict__ partk,
                             float* __restrict__ nq, float* __restrict__ nk, int L) {
    int l = blockIdx.x * 256 + threadIdx.x;
    if (l >= L) return;
    float sq = 0.f, sk = 0.f;
#pragma unroll
    for (int j = 0; j < 8; ++j) {
        sq += partq[(size_t)j * L + l];
        sk += partk[(size_t)j * L + l];
    }
    nq[l] = sq; nk[l] = sk;
}

// router: p[l] = 0.5*(1 - dot/(|q[l-1]||k[l]|)), dot = enc_f32[l-1] . t[l]
__global__ __launch_bounds__(256) void router_p2(const u16* __restrict__ ench,
                                                 const u16* __restrict__ encl,
                                                 const float* __restrict__ t,
                                                 const float* __restrict__ nq,
                                                 const float* __restrict__ nk,
                                                 float* __restrict__ p) {
    const int l = blockIdx.x + 1;
    ushort4 h  = ((const ushort4*)(ench + (size_t)(l - 1) * D_DIM))[threadIdx.x];
    ushort4 lo = ((const ushort4*)(encl + (size_t)(l - 1) * D_DIM))[threadIdx.x];
    float4  tv = ((const float4*)(t + (size_t)l * D_DIM))[threadIdx.x];
    float dot = (bf2f(h.x) + bf2f(lo.x)) * tv.x
              + (bf2f(h.y) + bf2f(lo.y)) * tv.y
              + (bf2f(h.z) + bf2f(lo.z)) * tv.z
              + (bf2f(h.w) + bf2f(lo.w)) * tv.w;
#pragma unroll
    for (int off = 32; off > 0; off >>= 1) dot += __shfl_down(dot, off);
    __shared__ float red[4];
    const int w = threadIdx.x >> 6;
    if ((threadIdx.x & 63) == 0) red[w] = dot;
    __syncthreads();
    if (threadIdx.x == 0) {
        dot = red[0] + red[1] + red[2] + red[3];
        float dn = fmaxf(sqrtf(nq[l - 1]), 1e-12f) * fmaxf(sqrtf(nk[l]), 1e-12f);
        p[l] = 0.5f * (1.f - dot / dn);
    }
}

__global__ void finalize_pab(const float* __restrict__ p, const int* __restrict__ cu,
                             int nseq, float* __restrict__ a, float* __restrict__ bs,
                             int L) {
    int l = blockIdx.x * 256 + threadIdx.x;
    if (l >= L) return;
    bool start = false;
    for (int s = 0; s < nseq; ++s) start = start || (cu[s] == l);
    float pv = (l == 0) ? 1.f : p[l];
    if (start) pv = 1.f;
    bool mask = pv > 0.5f;
    float pc  = fminf(fmaxf(pv, 1e-4f), 1.f - 1e-4f);
    a[l]  = start ? 0.f : (mask ? (1.f - pc) : 1.f);
    bs[l] = mask ? pc : 0.f;
}

// ---------------------------------------------------------------------------
// scan (bf16 m/y storage, f32 running state)
// ---------------------------------------------------------------------------
__global__ __launch_bounds__(256) void scan_local(const float* __restrict__ a,
                                                  const float* __restrict__ bs,
                                                  u16* __restrict__ m,
                                                  float* __restrict__ P) {
    __shared__ float a_s[CL], b_s[CL];
    const int chunk = blockIdx.x;
    const int d     = blockIdx.y * 256 + threadIdx.x;
    const int l0    = chunk * CL;
    for (int i = threadIdx.x; i < CL; i += 256) { a_s[i] = a[l0 + i]; b_s[i] = bs[l0 + i]; }
    __syncthreads();
    if (blockIdx.y == 0 && threadIdx.x == 0) {
        float pp = 1.f;
        for (int i = 0; i < CL; ++i) { pp *= a_s[i]; P[l0 + i] = pp; }
    }
    float h = 0.f;
    u16* mp = m + (size_t)l0 * D_DIM + d;
    for (int i = 0; i < CL; ++i) {
        float mv = bf2f(mp[(size_t)i * D_DIM]);
        h = fmaf(a_s[i], h, b_s[i] * mv);
        mp[(size_t)i * D_DIM] = f2bf(h);
    }
}

__global__ void scan_carry(const u16* __restrict__ y, const float* __restrict__ P,
                           float* __restrict__ carry, int nchunks) {
    const int d = blockIdx.x * 256 + threadIdx.x;
    float H = 0.f;
    for (int c = 0; c < nchunks; ++c) {
        carry[(size_t)c * D_DIM + d] = H;
        const float Ac = P[c * CL + (CL - 1)];
        const float Bc = bf2f(y[((size_t)c * CL + (CL - 1)) * D_DIM + d]);
        H = fmaf(Ac, H, Bc);
    }
}

// fixup in place: y = y_local + P[l]*carry  (bf16 in/out, 8 elems/thread)
__global__ void fixup_fuse(u16* __restrict__ y, const float* __restrict__ P,
                           const float* __restrict__ carry) {
    const size_t i8  = (size_t)blockIdx.x * 256 + threadIdx.x;
    const size_t idx = i8 * 8;
    const int l  = (int)(idx >> 10);
    const int dd = (int)(idx & 1023);
    const int c  = l >> 9;                    // CL = 512
    const float pl = P[l];
    short8 yv = *(short8*)(y + idx);
    const float4 c0 = *(const float4*)(carry + (size_t)c * D_DIM + dd);
    const float4 c1 = *(const float4*)(carry + (size_t)c * D_DIM + dd + 4);
    short8 o;
    o[0] = (short)f2bf(fmaf(pl, c0.x, bf2f((u16)yv[0])));
    o[1] = (short)f2bf(fmaf(pl, c0.y, bf2f((u16)yv[1])));
    o[2] = (short)f2bf(fmaf(pl, c0.z, bf2f((u16)yv[2])));
    o[3] = (short)f2bf(fmaf(pl, c0.w, bf2f((u16)yv[3])));
    o[4] = (short)f2bf(fmaf(pl, c1.x, bf2f((u16)yv[4])));
    o[5] = (short)f2bf(fmaf(pl, c1.y, bf2f((u16)yv[5])));
    o[6] = (short)f2bf(fmaf(pl, c1.z, bf2f((u16)yv[6])));
    o[7] = (short)f2bf(fmaf(pl, c1.w, bf2f((u16)yv[7])));
    *(short8*)(y + idx) = o;
}

// ---------------------------------------------------------------------------
extern "C" void kernel_launch(void* const* d_in, const int* in_sizes, int n_in,
                              void* d_out, int out_size, void* d_ws, size_t ws_size,
                              hipStream_t stream) {
    const float* x  = (const float*)d_in[0];
    const float* Wq = (const float*)d_in[1];
    const float* Wk = (const float*)d_in[2];
    const float* Wr = (const float*)d_in[3];
    const float* We = (const float*)d_in[4];
    const float* Wm = (const float*)d_in[5];
    const float* Wd = (const float*)d_in[6];
    const int*   cu = (const int*)d_in[7];
    const int L    = in_sizes[0] / D_DIM;      // 32768
    const int nseq = in_sizes[7] - 1;          // 4

    const size_t LD2 = (size_t)L * D_DIM * 2;  // 64 MiB bf16 plane
    const size_t DD  = (size_t)D_DIM * D_DIM;
    const int nLD4 = L * D_DIM / 4;
    const int nDD4 = (int)(DD / 4);
    const int nchunks = L / CL;

    // ws (256.5 MB):
    //   R1a [0,64M):    x_hi -> (t lower half) -> m bf16 -> ybf
    //   R1b [64M,128M): x_lo -> (t upper half) -> Wdb, Wdrb
    //   R2a [128M,192M): enc_hi      R2b [192M,256M): enc_lo
    //   scalars at 256M: p, av, bs, P (512 KB)
    char* ws = (char*)d_ws;
    u16*   xh   = (u16*)ws;
    u16*   xl   = (u16*)(ws + LD2);
    float* tbuf = (float*)ws;                  // 128MB f32 (over R1)
    u16*   mybuf= (u16*)ws;                    // m/y bf16 (R1a)
    u16*   Wdb  = (u16*)(ws + LD2);            // after t dead
    u16*   Wdrb = Wdb + DD;
    u16*   ench = (u16*)(ws + 2 * LD2);
    u16*   encl = (u16*)(ws + 3 * LD2);
    float* p    = (float*)(ws + 4 * LD2);
    float* av   = p  + L;
    float* bs   = av + L;
    float* P    = bs + L;

    // d_out scratch (all dead before final dec2 write):
    char* dob = (char*)d_out;
    u16* Weh   = (u16*)dob;
    u16* Wel   = (u16*)(dob + (2u << 20));
    u16* WqTh  = (u16*)(dob + (4u << 20));
    u16* WqTl  = (u16*)(dob + (6u << 20));
    u16* WkTh  = (u16*)(dob + (8u << 20));
    u16* WkTl  = (u16*)(dob + (10u << 20));
    float* Mf  = (float*)(dob + (12u << 20));
    u16* Mh    = (u16*)(dob + (16u << 20));
    u16* Ml    = (u16*)(dob + (18u << 20));
    u16* Wqb   = (u16*)(dob + (20u << 20));
    u16* Wkb   = (u16*)(dob + (22u << 20));
    u16* Wmb   = (u16*)(dob + (24u << 20));
    u16* WrTb  = (u16*)(dob + (26u << 20));
    float* partq = (float*)(dob + (28u << 20));
    float* partk = (float*)(dob + (29u << 20));
    float* nq    = (float*)(dob + (30u << 20));
    float* nk    = (float*)(dob + (30u << 20) + 131072);
    float* carry = (float*)(dob + (31u << 20));
    float* out = (float*)d_out;

    dim3 gL(L / 128, D_DIM / 128);            // (256, 8)
    dim3 gD(D_DIM / 128, D_DIM / 128);
    dim3 gT(D_DIM / 32, D_DIM / 32);

    // 1. splits
    split_bf16<<<(nLD4 + 255) / 256, 256, 0, stream>>>(x, xh, xl, nLD4);
    split_bf16<<<(nDD4 + 255) / 256, 256, 0, stream>>>(We, Weh, Wel, nDD4);
    // 2. enc (bf16x3) -> hi/lo planes directly
    gemm_bf16x3_nt<<<gL, 256, 0, stream>>>(xh, xl, Weh, Wel, nullptr, ench, encl);
    // 3. M = Wq^T @ Wk (bf16x3)
    transpose_split<<<gT, 256, 0, stream>>>(Wq, WqTh, WqTl);
    transpose_split<<<gT, 256, 0, stream>>>(Wk, WkTh, WkTl);
    gemm_bf16x3_nt<<<gD, 256, 0, stream>>>(WqTh, WqTl, WkTh, WkTl, Mf, nullptr, nullptr);
    split_bf16<<<(nDD4 + 255) / 256, 256, 0, stream>>>(Mf, Mh, Ml, nDD4);
    // 4. t = enc @ M^T (bf16x3, f32) -> R1 (x planes dead)
    gemm_bf16x3_nt<<<gL, 256, 0, stream>>>(ench, encl, Mh, Ml, tbuf, nullptr, nullptr);
    // 5. q,k norms via norm-only GEMMs
    conv_bf16<<<(nDD4 + 255) / 256, 256, 0, stream>>>(Wq, Wqb, nDD4);
    conv_bf16<<<(nDD4 + 255) / 256, 256, 0, stream>>>(Wk, Wkb, nDD4);
    gemm_norm<<<gL, 256, 0, stream>>>(ench, Wqb, partq);
    gemm_norm<<<gL, 256, 0, stream>>>(ench, Wkb, partk);
    combine_norm<<<(L + 255) / 256, 256, 0, stream>>>(partq, partk, nq, nk, L);
    // 6. router + gates
    router_p2<<<L - 1, 256, 0, stream>>>(ench, encl, tbuf, nq, nk, p);
    finalize_pab<<<(L + 255) / 256, 256, 0, stream>>>(p, cu, nseq, av, bs, L);
    // 7. m = enc @ Wm^T -> bf16 (t dead)
    conv_bf16<<<(nDD4 + 255) / 256, 256, 0, stream>>>(Wm, Wmb, nDD4);
    gemm_bf16_nt<<<gL, 256, 0, stream>>>(ench, Wmb, nullptr, mybuf);
    // 8. chunked scan in place (bf16)
    dim3 gsl(nchunks, D_DIM / 256);
    scan_local<<<gsl, 256, 0, stream>>>(av, bs, mybuf, P);
    scan_carry<<<D_DIM / 256, 256, 0, stream>>>(mybuf, P, carry, nchunks);
    fixup_fuse<<<(size_t)L * D_DIM / 8 / 256, 256, 0, stream>>>(mybuf, P, carry);
    // 9. Wdr = Wd @ Wr (for fused residual-decode); weights into ws R1b
    transpose_split<<<gT, 256, 0, stream>>>(Wr, WrTb, nullptr);
    conv_bf16<<<(nDD4 + 255) / 256, 256, 0, stream>>>(Wd, Wdb, nDD4);
    gemm_bf16_nt<<<gD, 256, 0, stream>>>(Wdb, WrTb, nullptr, Wdrb);
    // 10. out = y @ Wd^T + enc @ Wdr^T
    gemm_dec2<<<gL, 256, 0, stream>>>(mybuf, ench, Wdb, Wdrb, out);
}

// Round 5
// 1007.860 us; speedup vs baseline: 5.1476x; 1.1910x over previous
//
#include <hip/hip_runtime.h>
#include <math.h>

#define D_DIM 1024
#define CL 512   // scan chunk length

typedef __attribute__((ext_vector_type(8))) short short8;
typedef __attribute__((ext_vector_type(4))) float f32x4;
typedef unsigned short u16;

__device__ __forceinline__ u16 f2bf(float f) {
    unsigned int u = __float_as_uint(f);
    u += 0x7fff + ((u >> 16) & 1);          // round-to-nearest-even
    return (u16)(u >> 16);
}
__device__ __forceinline__ float bf2f(u16 h) {
    return __uint_as_float((unsigned int)h << 16);
}

#define GLOAD16(g, l) __builtin_amdgcn_global_load_lds(                      \
        (const __attribute__((address_space(1))) void*)(g),                  \
        (__attribute__((address_space(3))) void*)(l), 16, 0, 0)
#define SBAR()   __builtin_amdgcn_s_barrier()
#define SCHED0() __builtin_amdgcn_sched_barrier(0)
#define PRIO(x)  __builtin_amdgcn_s_setprio(x)
#define WAITVM(N) asm volatile("s_waitcnt vmcnt(" #N ")" ::: "memory")

// LDS swizzle (verified conflicts==0): data (row r, 16B-chunk c of 4) at byte
//   r*64 + (c ^ ((r>>1)&3))*16.  Staging writes linearly; global src chunk is
//   pre-inverse-swizzled with the same involution.

// ===========================================================================
// gemm256: plain bf16 MFMA GEMM, 256x256 tile, BK=32, 512 thr (8 waves 2Mx4N),
// 4 LDS buffers, counted-vmcnt pipeline (stage t+3 during t, vmcnt(8) at tile
// boundary). EPI: 0 = bf16 C, 1 = f32 C, 2 = norm partials (no C traffic).
// NPAIR: 1 normal (K=1024), 2 dual source (K=2048: A1@W1 then A2@W2 summed).
// ===========================================================================
template<int EPI, int NPAIR>
__global__ __launch_bounds__(512) void gemm256(const u16* __restrict__ A1,
                                               const u16* __restrict__ W1,
                                               const u16* __restrict__ A2,
                                               const u16* __restrict__ W2,
                                               float* __restrict__ Cf,
                                               u16* __restrict__ Cb) {
    constexpr int NT = NPAIR * 32;
    __shared__ u16 lds[4 * 16384];      // 4 bufs x (A 16KB + B 16KB) = 128 KB
    __shared__ float nsum[4][256];
    const int tid = threadIdx.x;
    const int lane = tid & 63, wid = tid >> 6;
    const int wm = wid >> 2, wn = wid & 3;
    const int fr = lane & 15, fq = lane >> 4;
    const int row0 = blockIdx.x * 256, col0 = blockIdx.y * 256;
    const int r0s = tid >> 2, c0s = tid & 3;

    int offA[8], offB[4];
#pragma unroll
    for (int i = 0; i < 8; ++i) {
        const int r = wm * 128 + i * 16 + fr;
        offA[i] = r * 64 + ((fq ^ ((r >> 1) & 3)) << 4);
    }
#pragma unroll
    for (int j = 0; j < 4; ++j) {
        const int r = wn * 64 + j * 16 + fr;
        offB[j] = r * 64 + ((fq ^ ((r >> 1) & 3)) << 4);
    }

    auto stageA = [&](int s) {
        const u16* src = (NPAIR == 2 && s >= 32) ? A2 : A1;
        const int k0 = (NPAIR == 2 ? (s & 31) : s) * 32;
        char* dst = (char*)lds + (s & 3) * 32768;
#pragma unroll
        for (int j = 0; j < 2; ++j) {
            const int r = j * 128 + r0s;
            const int c = c0s ^ ((r >> 1) & 3);
            GLOAD16(src + (size_t)(row0 + r) * D_DIM + k0 + c * 8,
                    dst + j * 8192 + tid * 16);
        }
    };
    auto stageB = [&](int s) {
        const u16* src = (NPAIR == 2 && s >= 32) ? W2 : W1;
        const int k0 = (NPAIR == 2 ? (s & 31) : s) * 32;
        char* dst = (char*)lds + (s & 3) * 32768 + 16384;
#pragma unroll
        for (int j = 0; j < 2; ++j) {
            const int r = j * 128 + r0s;
            const int c = c0s ^ ((r >> 1) & 3);
            GLOAD16(src + (size_t)(col0 + r) * D_DIM + k0 + c * 8,
                    dst + j * 8192 + tid * 16);
        }
    };

    f32x4 acc[8][4];
#pragma unroll
    for (int i = 0; i < 8; ++i)
#pragma unroll
        for (int j = 0; j < 4; ++j) acc[i][j] = (f32x4){0.f, 0.f, 0.f, 0.f};

    // prologue: tiles 0..2 staged; wait for tile 0 (8 newest stay in flight)
    stageA(0); stageB(0); stageA(1); stageB(1); stageA(2); stageB(2);
    WAITVM(8); SBAR(); SCHED0();

    for (int t = 0; t < NT; ++t) {
        const char* buf  = (const char*)lds + (t & 3) * 32768;
        const char* bufB = buf + 16384;
        short8 af[8], bf[4];
        // ---- phase 0: lower half of C rows
#pragma unroll
        for (int i = 0; i < 4; ++i) af[i] = *(const short8*)(buf + offA[i]);
#pragma unroll
        for (int j = 0; j < 4; ++j) bf[j] = *(const short8*)(bufB + offB[j]);
        if (t + 3 < NT) stageA(t + 3);
        SBAR();
        PRIO(1);
#pragma unroll
        for (int i = 0; i < 4; ++i)
#pragma unroll
            for (int j = 0; j < 4; ++j)
                acc[i][j] = __builtin_amdgcn_mfma_f32_16x16x32_bf16(af[i], bf[j], acc[i][j], 0, 0, 0);
        PRIO(0);
        // ---- phase 1: upper half
#pragma unroll
        for (int i = 4; i < 8; ++i) af[i] = *(const short8*)(buf + offA[i]);
        if (t + 3 < NT) stageB(t + 3);
        SBAR();
        PRIO(1);
#pragma unroll
        for (int i = 4; i < 8; ++i)
#pragma unroll
            for (int j = 0; j < 4; ++j)
                acc[i][j] = __builtin_amdgcn_mfma_f32_16x16x32_bf16(af[i], bf[j], acc[i][j], 0, 0, 0);
        PRIO(0);
        // ---- tile boundary: next tile's data must be landed (counted wait)
        if (t + 1 < NT) {
            if (t + 3 < NT)      { WAITVM(8); }
            else if (t + 2 < NT) { WAITVM(4); }
            else                 { WAITVM(0); }
            SBAR(); SCHED0();
        }
    }

    if (EPI == 2) {
        // per-row sum of squares over full 256-col tile
#pragma unroll
        for (int i = 0; i < 8; ++i)
#pragma unroll
            for (int rr = 0; rr < 4; ++rr) {
                float s = acc[i][0][rr] * acc[i][0][rr] + acc[i][1][rr] * acc[i][1][rr]
                        + acc[i][2][rr] * acc[i][2][rr] + acc[i][3][rr] * acc[i][3][rr];
#pragma unroll
                for (int off = 1; off < 16; off <<= 1) s += __shfl_xor(s, off);
                if (fr == 0) nsum[wn][wm * 128 + i * 16 + fq * 4 + rr] = s;
            }
        __syncthreads();
        if (tid < 256)
            Cf[(size_t)blockIdx.y * (gridDim.x * 256) + row0 + tid] =
                nsum[0][tid] + nsum[1][tid] + nsum[2][tid] + nsum[3][tid];
    } else {
#pragma unroll
        for (int i = 0; i < 8; ++i)
#pragma unroll
            for (int j = 0; j < 4; ++j) {
                const int r0 = row0 + wm * 128 + i * 16 + fq * 4;
                const int c  = col0 + wn * 64 + j * 16 + fr;
#pragma unroll
                for (int rr = 0; rr < 4; ++rr) {
                    if (EPI == 0) Cb[(size_t)(r0 + rr) * D_DIM + c] = f2bf(acc[i][j][rr]);
                    else          Cf[(size_t)(r0 + rr) * D_DIM + c] = acc[i][j][rr];
                }
            }
    }
}

// ===========================================================================
// gemm_x3: split-precision bf16x3 GEMM (Ah@Wh + Ah@Wl + Al@Wh), 128x256 tile,
// BK=32, 512 thr (8 waves 2Mx4N), 3 LDS buffers (144 KB), stage t+2, vmcnt(6).
// 3 phases per tile = the three plane products. EPI: 0 = hi/lo bf16 split out,
// 1 = f32 out.
// ===========================================================================
template<int EPI>
__global__ __launch_bounds__(512) void gemm_x3(const u16* __restrict__ Ah,
                                               const u16* __restrict__ Al,
                                               const u16* __restrict__ Wh,
                                               const u16* __restrict__ Wl,
                                               float* __restrict__ Cf,
                                               u16* __restrict__ Chi,
                                               u16* __restrict__ Clo) {
    constexpr int NT = 32;
    // per buf bytes: Ah 8192 | Al 8192 | Bh 16384 | Bl 16384 = 49152
    __shared__ u16 lds[3 * 24576];
    const int tid = threadIdx.x;
    const int lane = tid & 63, wid = tid >> 6;
    const int wm = wid >> 2, wn = wid & 3;
    const int fr = lane & 15, fq = lane >> 4;
    const int row0 = blockIdx.x * 128, col0 = blockIdx.y * 256;
    const int r0s = tid >> 2, c0s = tid & 3;

    int offA[4], offB[4];
#pragma unroll
    for (int i = 0; i < 4; ++i) {
        const int r = wm * 64 + i * 16 + fr;
        offA[i] = r * 64 + ((fq ^ ((r >> 1) & 3)) << 4);
    }
#pragma unroll
    for (int j = 0; j < 4; ++j) {
        const int r = wn * 64 + j * 16 + fr;
        offB[j] = r * 64 + ((fq ^ ((r >> 1) & 3)) << 4);
    }

    auto stageAhl = [&](int s) {   // both A planes: 2 loads
        char* base = (char*)lds + (s % 3) * 49152;
        const int r = r0s;
        const int c = c0s ^ ((r >> 1) & 3);
        const size_t g = (size_t)(row0 + r) * D_DIM + s * 32 + c * 8;
        GLOAD16(Ah + g, base + tid * 16);
        GLOAD16(Al + g, base + 8192 + tid * 16);
    };
    auto stageBh = [&](int s) {    // 2 loads
        char* base = (char*)lds + (s % 3) * 49152 + 16384;
#pragma unroll
        for (int j = 0; j < 2; ++j) {
            const int r = j * 128 + r0s;
            const int c = c0s ^ ((r >> 1) & 3);
            GLOAD16(Wh + (size_t)(col0 + r) * D_DIM + s * 32 + c * 8,
                    base + j * 8192 + tid * 16);
        }
    };
    auto stageBl = [&](int s) {    // 2 loads
        char* base = (char*)lds + (s % 3) * 49152 + 32768;
#pragma unroll
        for (int j = 0; j < 2; ++j) {
            const int r = j * 128 + r0s;
            const int c = c0s ^ ((r >> 1) & 3);
            GLOAD16(Wl + (size_t)(col0 + r) * D_DIM + s * 32 + c * 8,
                    base + j * 8192 + tid * 16);
        }
    };

    f32x4 acc[4][4];
#pragma unroll
    for (int i = 0; i < 4; ++i)
#pragma unroll
        for (int j = 0; j < 4; ++j) acc[i][j] = (f32x4){0.f, 0.f, 0.f, 0.f};

    stageAhl(0); stageBh(0); stageBl(0);
    stageAhl(1); stageBh(1); stageBl(1);
    WAITVM(6); SBAR(); SCHED0();

    for (int t = 0; t < NT; ++t) {
        const char* base = (const char*)lds + (t % 3) * 49152;
        short8 afh[4], afl[4], bfh[4], bfl[4];
        // ---- phase 0: hi*hi
#pragma unroll
        for (int i = 0; i < 4; ++i) afh[i] = *(const short8*)(base + offA[i]);
#pragma unroll
        for (int j = 0; j < 4; ++j) bfh[j] = *(const short8*)(base + 16384 + offB[j]);
        if (t + 2 < NT) stageBh(t + 2);
        SBAR();
        PRIO(1);
#pragma unroll
        for (int i = 0; i < 4; ++i)
#pragma unroll
            for (int j = 0; j < 4; ++j)
                acc[i][j] = __builtin_amdgcn_mfma_f32_16x16x32_bf16(afh[i], bfh[j], acc[i][j], 0, 0, 0);
        PRIO(0);
        // ---- phase 1: hi*lo
#pragma unroll
        for (int j = 0; j < 4; ++j) bfl[j] = *(const short8*)(base + 32768 + offB[j]);
        if (t + 2 < NT) stageBl(t + 2);
        SBAR();
        PRIO(1);
#pragma unroll
        for (int i = 0; i < 4; ++i)
#pragma unroll
            for (int j = 0; j < 4; ++j)
                acc[i][j] = __builtin_amdgcn_mfma_f32_16x16x32_bf16(afh[i], bfl[j], acc[i][j], 0, 0, 0);
        PRIO(0);
        // ---- phase 2: lo*hi
#pragma unroll
        for (int i = 0; i < 4; ++i) afl[i] = *(const short8*)(base + 8192 + offA[i]);
        if (t + 2 < NT) stageAhl(t + 2);
        SBAR();
        PRIO(1);
#pragma unroll
        for (int i = 0; i < 4; ++i)
#pragma unroll
            for (int j = 0; j < 4; ++j)
                acc[i][j] = __builtin_amdgcn_mfma_f32_16x16x32_bf16(afl[i], bfh[j], acc[i][j], 0, 0, 0);
        PRIO(0);
        // ---- tile boundary
        if (t + 1 < NT) {
            if (t + 2 < NT) { WAITVM(6); }
            else            { WAITVM(0); }
            SBAR(); SCHED0();
        }
    }

#pragma unroll
    for (int i = 0; i < 4; ++i)
#pragma unroll
        for (int j = 0; j < 4; ++j) {
            const int r0 = row0 + wm * 64 + i * 16 + fq * 4;
            const int c  = col0 + wn * 64 + j * 16 + fr;
#pragma unroll
            for (int rr = 0; rr < 4; ++rr) {
                const float v = acc[i][j][rr];
                if (EPI == 0) {
                    const u16 h = f2bf(v);
                    Chi[(size_t)(r0 + rr) * D_DIM + c] = h;
                    Clo[(size_t)(r0 + rr) * D_DIM + c] = f2bf(v - bf2f(h));
                } else {
                    Cf[(size_t)(r0 + rr) * D_DIM + c] = v;
                }
            }
        }
}

// ---------------------------------------------------------------------------
// m97-style 128-tile plain bf16 GEMM (kept for tiny D x D work)
// ---------------------------------------------------------------------------
__global__ __launch_bounds__(256) void gemm_bf16_nt(const u16* __restrict__ A,
                                                    const u16* __restrict__ W,
                                                    float* __restrict__ C,
                                                    u16* __restrict__ Cbf) {
    __shared__ u16 lA[128 * 32];
    __shared__ u16 lB[128 * 32];
    const int tid  = threadIdx.x;
    const int lane = tid & 63, wid = tid >> 6;
    const int wy = wid & 1, wx = wid >> 1;
    const int fr = lane & 15, fq = lane >> 4;
    const int row0 = blockIdx.x * 128;
    const int col0 = blockIdx.y * 128;

    const int rS   = tid >> 2;
    const int subS = (tid & 3) ^ ((rS >> 1) & 3);
    const u16* gA = A + (size_t)(row0 + rS) * D_DIM + subS * 8;
    const u16* gB = W + (size_t)(col0 + rS) * D_DIM + subS * 8;
    char* lA0 = (char*)lA + tid * 16;
    char* lB0 = (char*)lB + tid * 16;
    const size_t rowStep = (size_t)64 * D_DIM;

    int offA[4], offB[4];
#pragma unroll
    for (int i = 0; i < 4; ++i) {
        const int ra = wy * 64 + i * 16 + fr;
        const int rb = wx * 64 + i * 16 + fr;
        offA[i] = ra * 64 + ((fq ^ ((ra >> 1) & 3)) << 4);
        offB[i] = rb * 64 + ((fq ^ ((rb >> 1) & 3)) << 4);
    }

    f32x4 acc[4][4];
#pragma unroll
    for (int i = 0; i < 4; ++i)
#pragma unroll
        for (int j = 0; j < 4; ++j) acc[i][j] = (f32x4){0.f, 0.f, 0.f, 0.f};

    for (int k0 = 0; k0 < D_DIM; k0 += 32) {
        __syncthreads();
        GLOAD16(gA + k0, lA0);
        GLOAD16(gA + k0 + rowStep, lA0 + 4096);
        GLOAD16(gB + k0, lB0);
        GLOAD16(gB + k0 + rowStep, lB0 + 4096);
        __syncthreads();
        short8 af[4], bf[4];
#pragma unroll
        for (int i = 0; i < 4; ++i) af[i] = *(const short8*)((const char*)lA + offA[i]);
#pragma unroll
        for (int j = 0; j < 4; ++j) bf[j] = *(const short8*)((const char*)lB + offB[j]);
#pragma unroll
        for (int i = 0; i < 4; ++i)
#pragma unroll
            for (int j = 0; j < 4; ++j)
                acc[i][j] = __builtin_amdgcn_mfma_f32_16x16x32_bf16(af[i], bf[j], acc[i][j], 0, 0, 0);
    }
#pragma unroll
    for (int i = 0; i < 4; ++i)
#pragma unroll
        for (int j = 0; j < 4; ++j) {
            const int r0 = row0 + wy * 64 + i * 16 + fq * 4;
            const int c  = col0 + wx * 64 + j * 16 + fr;
            if (Cbf) {
#pragma unroll
                for (int r = 0; r < 4; ++r)
                    Cbf[(size_t)(r0 + r) * D_DIM + c] = f2bf(acc[i][j][r]);
            } else {
#pragma unroll
                for (int r = 0; r < 4; ++r)
                    C[(size_t)(r0 + r) * D_DIM + c] = acc[i][j][r];
            }
        }
}

// ---------------------------------------------------------------------------
// small kernels
// ---------------------------------------------------------------------------
__global__ void split_bf16(const float* __restrict__ src, u16* __restrict__ hi,
                           u16* __restrict__ lo, int n4) {
    int i = blockIdx.x * 256 + threadIdx.x;
    if (i >= n4) return;
    float4 v = ((const float4*)src)[i];
    ushort4 h, l;
    h.x = f2bf(v.x); l.x = f2bf(v.x - bf2f(h.x));
    h.y = f2bf(v.y); l.y = f2bf(v.y - bf2f(h.y));
    h.z = f2bf(v.z); l.z = f2bf(v.z - bf2f(h.z));
    h.w = f2bf(v.w); l.w = f2bf(v.w - bf2f(h.w));
    ((ushort4*)hi)[i] = h;
    ((ushort4*)lo)[i] = l;
}

__global__ void conv_bf16(const float* __restrict__ src, u16* __restrict__ dst, int n4) {
    int i = blockIdx.x * 256 + threadIdx.x;
    if (i >= n4) return;
    float4 v = ((const float4*)src)[i];
    ushort4 o = {f2bf(v.x), f2bf(v.y), f2bf(v.z), f2bf(v.w)};
    ((ushort4*)dst)[i] = o;
}

__global__ __launch_bounds__(256) void transpose_split(const float* __restrict__ W,
                                                       u16* __restrict__ Th,
                                                       u16* __restrict__ Tl) {
    __shared__ float tile[32][33];
    const int e0 = blockIdx.x * 32, d0 = blockIdx.y * 32;
    const int tx = threadIdx.x & 31, ty = threadIdx.x >> 5;
#pragma unroll
    for (int i = 0; i < 32; i += 8)
        tile[ty + i][tx] = W[(size_t)(e0 + ty + i) * D_DIM + d0 + tx];
    __syncthreads();
#pragma unroll
    for (int i = 0; i < 32; i += 8) {
        float v = tile[tx][ty + i];
        u16 h = f2bf(v);
        Th[(size_t)(d0 + ty + i) * D_DIM + e0 + tx] = h;
        if (Tl) Tl[(size_t)(d0 + ty + i) * D_DIM + e0 + tx] = f2bf(v - bf2f(h));
    }
}

__global__ void combine_norm(const float* __restrict__ partq, const float* __restrict__ partk,
                             float* __restrict__ nq, float* __restrict__ nk, int L) {
    int l = blockIdx.x * 256 + threadIdx.x;
    if (l >= L) return;
    float sq = 0.f, sk = 0.f;
#pragma unroll
    for (int j = 0; j < 4; ++j) {
        sq += partq[(size_t)j * L + l];
        sk += partk[(size_t)j * L + l];
    }
    nq[l] = sq; nk[l] = sk;
}

__global__ __launch_bounds__(256) void router_p2(const u16* __restrict__ ench,
                                                 const u16* __restrict__ encl,
                                                 const float* __restrict__ t,
                                                 const float* __restrict__ nq,
                                                 const float* __restrict__ nk,
                                                 float* __restrict__ p) {
    const int l = blockIdx.x + 1;
    ushort4 h  = ((const ushort4*)(ench + (size_t)(l - 1) * D_DIM))[threadIdx.x];
    ushort4 lo = ((const ushort4*)(encl + (size_t)(l - 1) * D_DIM))[threadIdx.x];
    float4  tv = ((const float4*)(t + (size_t)l * D_DIM))[threadIdx.x];
    float dot = (bf2f(h.x) + bf2f(lo.x)) * tv.x
              + (bf2f(h.y) + bf2f(lo.y)) * tv.y
              + (bf2f(h.z) + bf2f(lo.z)) * tv.z
              + (bf2f(h.w) + bf2f(lo.w)) * tv.w;
#pragma unroll
    for (int off = 32; off > 0; off >>= 1) dot += __shfl_down(dot, off);
    __shared__ float red[4];
    const int w = threadIdx.x >> 6;
    if ((threadIdx.x & 63) == 0) red[w] = dot;
    __syncthreads();
    if (threadIdx.x == 0) {
        dot = red[0] + red[1] + red[2] + red[3];
        float dn = fmaxf(sqrtf(nq[l - 1]), 1e-12f) * fmaxf(sqrtf(nk[l]), 1e-12f);
        p[l] = 0.5f * (1.f - dot / dn);
    }
}

__global__ void finalize_pab(const float* __restrict__ p, const int* __restrict__ cu,
                             int nseq, float* __restrict__ a, float* __restrict__ bs,
                             int L) {
    int l = blockIdx.x * 256 + threadIdx.x;
    if (l >= L) return;
    bool start = false;
    for (int s = 0; s < nseq; ++s) start = start || (cu[s] == l);
    float pv = (l == 0) ? 1.f : p[l];
    if (start) pv = 1.f;
    bool mask = pv > 0.5f;
    float pc  = fminf(fmaxf(pv, 1e-4f), 1.f - 1e-4f);
    a[l]  = start ? 0.f : (mask ? (1.f - pc) : 1.f);
    bs[l] = mask ? pc : 0.f;
}

// ---------------------------------------------------------------------------
// scan (bf16 m/y storage, f32 running state)
// ---------------------------------------------------------------------------
__global__ __launch_bounds__(256) void scan_local(const float* __restrict__ a,
                                                  const float* __restrict__ bs,
                                                  u16* __restrict__ m,
                                                  float* __restrict__ P) {
    __shared__ float a_s[CL], b_s[CL];
    const int chunk = blockIdx.x;
    const int d     = blockIdx.y * 256 + threadIdx.x;
    const int l0    = chunk * CL;
    for (int i = threadIdx.x; i < CL; i += 256) { a_s[i] = a[l0 + i]; b_s[i] = bs[l0 + i]; }
    __syncthreads();
    if (blockIdx.y == 0 && threadIdx.x == 0) {
        float pp = 1.f;
        for (int i = 0; i < CL; ++i) { pp *= a_s[i]; P[l0 + i] = pp; }
    }
    float h = 0.f;
    u16* mp = m + (size_t)l0 * D_DIM + d;
    for (int i = 0; i < CL; ++i) {
        float mv = bf2f(mp[(size_t)i * D_DIM]);
        h = fmaf(a_s[i], h, b_s[i] * mv);
        mp[(size_t)i * D_DIM] = f2bf(h);
    }
}

__global__ void scan_carry(const u16* __restrict__ y, const float* __restrict__ P,
                           float* __restrict__ carry, int nchunks) {
    const int d = blockIdx.x * 256 + threadIdx.x;
    float H = 0.f;
    for (int c = 0; c < nchunks; ++c) {
        carry[(size_t)c * D_DIM + d] = H;
        const float Ac = P[c * CL + (CL - 1)];
        const float Bc = bf2f(y[((size_t)c * CL + (CL - 1)) * D_DIM + d]);
        H = fmaf(Ac, H, Bc);
    }
}

__global__ void fixup_fuse(u16* __restrict__ y, const float* __restrict__ P,
                           const float* __restrict__ carry) {
    const size_t i8  = (size_t)blockIdx.x * 256 + threadIdx.x;
    const size_t idx = i8 * 8;
    const int l  = (int)(idx >> 10);
    const int dd = (int)(idx & 1023);
    const int c  = l >> 9;                    // CL = 512
    const float pl = P[l];
    short8 yv = *(short8*)(y + idx);
    const float4 c0 = *(const float4*)(carry + (size_t)c * D_DIM + dd);
    const float4 c1 = *(const float4*)(carry + (size_t)c * D_DIM + dd + 4);
    short8 o;
    o[0] = (short)f2bf(fmaf(pl, c0.x, bf2f((u16)yv[0])));
    o[1] = (short)f2bf(fmaf(pl, c0.y, bf2f((u16)yv[1])));
    o[2] = (short)f2bf(fmaf(pl, c0.z, bf2f((u16)yv[2])));
    o[3] = (short)f2bf(fmaf(pl, c0.w, bf2f((u16)yv[3])));
    o[4] = (short)f2bf(fmaf(pl, c1.x, bf2f((u16)yv[4])));
    o[5] = (short)f2bf(fmaf(pl, c1.y, bf2f((u16)yv[5])));
    o[6] = (short)f2bf(fmaf(pl, c1.z, bf2f((u16)yv[6])));
    o[7] = (short)f2bf(fmaf(pl, c1.w, bf2f((u16)yv[7])));
    *(short8*)(y + idx) = o;
}

// ---------------------------------------------------------------------------
extern "C" void kernel_launch(void* const* d_in, const int* in_sizes, int n_in,
                              void* d_out, int out_size, void* d_ws, size_t ws_size,
                              hipStream_t stream) {
    const float* x  = (const float*)d_in[0];
    const float* Wq = (const float*)d_in[1];
    const float* Wk = (const float*)d_in[2];
    const float* Wr = (const float*)d_in[3];
    const float* We = (const float*)d_in[4];
    const float* Wm = (const float*)d_in[5];
    const float* Wd = (const float*)d_in[6];
    const int*   cu = (const int*)d_in[7];
    const int L    = in_sizes[0] / D_DIM;      // 32768
    const int nseq = in_sizes[7] - 1;          // 4

    const size_t LD2 = (size_t)L * D_DIM * 2;  // 64 MiB bf16 plane
    const size_t DD  = (size_t)D_DIM * D_DIM;
    const int nLD4 = L * D_DIM / 4;
    const int nDD4 = (int)(DD / 4);
    const int nchunks = L / CL;

    // ws:
    //   R1a [0,64M):    x_hi -> (t lower half) -> m bf16 -> ybf
    //   R1b [64M,128M): x_lo -> (t upper half) -> Wdb, Wdrb
    //   R2a [128M,192M): enc_hi      R2b [192M,256M): enc_lo
    //   scalars at 256M
    char* ws = (char*)d_ws;
    u16*   xh   = (u16*)ws;
    u16*   xl   = (u16*)(ws + LD2);
    float* tbuf = (float*)ws;
    u16*   mybuf= (u16*)ws;
    u16*   Wdb  = (u16*)(ws + LD2);
    u16*   Wdrb = Wdb + DD;
    u16*   ench = (u16*)(ws + 2 * LD2);
    u16*   encl = (u16*)(ws + 3 * LD2);
    float* p    = (float*)(ws + 4 * LD2);
    float* av   = p  + L;
    float* bs   = av + L;
    float* P    = bs + L;

    // d_out scratch (all dead before final dec2 write):
    char* dob = (char*)d_out;
    u16* Weh   = (u16*)dob;
    u16* Wel   = (u16*)(dob + (2u << 20));
    u16* WqTh  = (u16*)(dob + (4u << 20));
    u16* WqTl  = (u16*)(dob + (6u << 20));
    u16* WkTh  = (u16*)(dob + (8u << 20));
    u16* WkTl  = (u16*)(dob + (10u << 20));
    float* Mf  = (float*)(dob + (12u << 20));
    u16* Mh    = (u16*)(dob + (16u << 20));
    u16* Ml    = (u16*)(dob + (18u << 20));
    u16* Wqb   = (u16*)(dob + (20u << 20));
    u16* Wkb   = (u16*)(dob + (22u << 20));
    u16* Wmb   = (u16*)(dob + (24u << 20));
    u16* WrTb  = (u16*)(dob + (26u << 20));
    float* partq = (float*)(dob + (28u << 20));   // [4][L] = 512 KB
    float* partk = (float*)(dob + (29u << 20));
    float* nq    = (float*)(dob + (30u << 20));
    float* nk    = (float*)(dob + (30u << 20) + 131072);
    float* carry = (float*)(dob + (31u << 20));
    float* out = (float*)d_out;

    dim3 gX3L(L / 128, D_DIM / 256);           // (256, 4)
    dim3 gX3D(D_DIM / 128, D_DIM / 256);       // (8, 4)
    dim3 g256(L / 256, D_DIM / 256);           // (128, 4)
    dim3 gD(D_DIM / 128, D_DIM / 128);         // (8, 8)
    dim3 gT(D_DIM / 32, D_DIM / 32);

    // 1. splits
    split_bf16<<<(nLD4 + 255) / 256, 256, 0, stream>>>(x, xh, xl, nLD4);
    split_bf16<<<(nDD4 + 255) / 256, 256, 0, stream>>>(We, Weh, Wel, nDD4);
    // 2. enc (x3) -> hi/lo planes
    gemm_x3<0><<<gX3L, 512, 0, stream>>>(xh, xl, Weh, Wel, nullptr, ench, encl);
    // 3. M = Wq^T @ Wk (x3)
    transpose_split<<<gT, 256, 0, stream>>>(Wq, WqTh, WqTl);
    transpose_split<<<gT, 256, 0, stream>>>(Wk, WkTh, WkTl);
    gemm_x3<1><<<gX3D, 512, 0, stream>>>(WqTh, WqTl, WkTh, WkTl, Mf, nullptr, nullptr);
    split_bf16<<<(nDD4 + 255) / 256, 256, 0, stream>>>(Mf, Mh, Ml, nDD4);
    // 4. t = enc @ M^T (x3, f32) over dead x planes
    gemm_x3<1><<<gX3L, 512, 0, stream>>>(ench, encl, Mh, Ml, tbuf, nullptr, nullptr);
    // 5. q,k norms (norm-only 256-tile GEMMs)
    conv_bf16<<<(nDD4 + 255) / 256, 256, 0, stream>>>(Wq, Wqb, nDD4);
    conv_bf16<<<(nDD4 + 255) / 256, 256, 0, stream>>>(Wk, Wkb, nDD4);
    gemm256<2, 1><<<g256, 512, 0, stream>>>(ench, Wqb, nullptr, nullptr, partq, nullptr);
    gemm256<2, 1><<<g256, 512, 0, stream>>>(ench, Wkb, nullptr, nullptr, partk, nullptr);
    combine_norm<<<(L + 255) / 256, 256, 0, stream>>>(partq, partk, nq, nk, L);
    // 6. router + gates
    router_p2<<<L - 1, 256, 0, stream>>>(ench, encl, tbuf, nq, nk, p);
    finalize_pab<<<(L + 255) / 256, 256, 0, stream>>>(p, cu, nseq, av, bs, L);
    // 7. m = enc @ Wm^T -> bf16 (t dead)
    conv_bf16<<<(nDD4 + 255) / 256, 256, 0, stream>>>(Wm, Wmb, nDD4);
    gemm256<0, 1><<<g256, 512, 0, stream>>>(ench, Wmb, nullptr, nullptr, nullptr, mybuf);
    // 8. chunked scan in place (bf16)
    dim3 gsl(nchunks, D_DIM / 256);
    scan_local<<<gsl, 256, 0, stream>>>(av, bs, mybuf, P);
    scan_carry<<<D_DIM / 256, 256, 0, stream>>>(mybuf, P, carry, nchunks);
    fixup_fuse<<<(size_t)L * D_DIM / 8 / 256, 256, 0, stream>>>(mybuf, P, carry);
    // 9. Wdr = Wd @ Wr (tiny, m97 kernel)
    transpose_split<<<gT, 256, 0, stream>>>(Wr, WrTb, nullptr);
    conv_bf16<<<(nDD4 + 255) / 256, 256, 0, stream>>>(Wd, Wdb, nDD4);
    gemm_bf16_nt<<<gD, 256, 0, stream>>>(Wdb, WrTb, nullptr, Wdrb);
    // 10. out = y @ Wd^T + enc @ Wdr^T (dual-K 256-tile)
    gemm256<1, 2><<<g256, 512, 0, stream>>>(mybuf, Wdb, ench, Wdrb, out, nullptr);
}

// Round 6
// 1002.128 us; speedup vs baseline: 5.1771x; 1.0057x over previous
//
#include <hip/hip_runtime.h>
#include <math.h>

#define D_DIM 1024
#define CL 512   // scan chunk length

typedef __attribute__((ext_vector_type(8))) short short8;
typedef __attribute__((ext_vector_type(4))) float f32x4;
typedef unsigned short u16;

__device__ __forceinline__ u16 f2bf(float f) {
    unsigned int u = __float_as_uint(f);
    u += 0x7fff + ((u >> 16) & 1);          // round-to-nearest-even
    return (u16)(u >> 16);
}
__device__ __forceinline__ float bf2f(u16 h) {
    return __uint_as_float((unsigned int)h << 16);
}

#define GLOAD16(g, l) __builtin_amdgcn_global_load_lds(                      \
        (const __attribute__((address_space(1))) void*)(g),                  \
        (__attribute__((address_space(3))) void*)(l), 16, 0, 0)
#define SBAR()   __builtin_amdgcn_s_barrier()
#define SCHED0() __builtin_amdgcn_sched_barrier(0)
#define PRIO(x)  __builtin_amdgcn_s_setprio(x)
#define WAITVM(N) asm volatile("s_waitcnt vmcnt(" #N ")" ::: "memory")

// LDS swizzle (verified conflicts==0): (row r, 16B-chunk c) at byte
//   r*64 + (c ^ ((r>>1)&3))*16;  staging pre-inverse-swizzles the global src.

// ===========================================================================
// gemm256: plain bf16 GEMM, 256x256 tile, BK=32, 512 thr, 4 LDS bufs,
// counted-vmcnt pipeline. EPI: 0 = bf16 C, 1 = f32 C.
// ===========================================================================
template<int EPI>
__global__ __launch_bounds__(512) void gemm256(const u16* __restrict__ A1,
                                               const u16* __restrict__ W1,
                                               float* __restrict__ Cf,
                                               u16* __restrict__ Cb) {
    constexpr int NT = 32;
    __shared__ u16 lds[4 * 16384];
    const int tid = threadIdx.x;
    const int lane = tid & 63, wid = tid >> 6;
    const int wm = wid >> 2, wn = wid & 3;
    const int fr = lane & 15, fq = lane >> 4;
    const int row0 = blockIdx.x * 256, col0 = blockIdx.y * 256;
    const int r0s = tid >> 2, c0s = tid & 3;

    int offA[8], offB[4];
#pragma unroll
    for (int i = 0; i < 8; ++i) {
        const int r = wm * 128 + i * 16 + fr;
        offA[i] = r * 64 + ((fq ^ ((r >> 1) & 3)) << 4);
    }
#pragma unroll
    for (int j = 0; j < 4; ++j) {
        const int r = wn * 64 + j * 16 + fr;
        offB[j] = r * 64 + ((fq ^ ((r >> 1) & 3)) << 4);
    }

    auto stageA = [&](int s) {
        const int k0 = s * 32;
        char* dst = (char*)lds + (s & 3) * 32768;
#pragma unroll
        for (int j = 0; j < 2; ++j) {
            const int r = j * 128 + r0s;
            const int c = c0s ^ ((r >> 1) & 3);
            GLOAD16(A1 + (size_t)(row0 + r) * D_DIM + k0 + c * 8,
                    dst + j * 8192 + tid * 16);
        }
    };
    auto stageB = [&](int s) {
        const int k0 = s * 32;
        char* dst = (char*)lds + (s & 3) * 32768 + 16384;
#pragma unroll
        for (int j = 0; j < 2; ++j) {
            const int r = j * 128 + r0s;
            const int c = c0s ^ ((r >> 1) & 3);
            GLOAD16(W1 + (size_t)(col0 + r) * D_DIM + k0 + c * 8,
                    dst + j * 8192 + tid * 16);
        }
    };

    f32x4 acc[8][4];
#pragma unroll
    for (int i = 0; i < 8; ++i)
#pragma unroll
        for (int j = 0; j < 4; ++j) acc[i][j] = (f32x4){0.f, 0.f, 0.f, 0.f};

    stageA(0); stageB(0); stageA(1); stageB(1); stageA(2); stageB(2);
    WAITVM(8); SBAR(); SCHED0();

    for (int t = 0; t < NT; ++t) {
        const char* buf  = (const char*)lds + (t & 3) * 32768;
        const char* bufB = buf + 16384;
        short8 af[8], bf[4];
#pragma unroll
        for (int i = 0; i < 4; ++i) af[i] = *(const short8*)(buf + offA[i]);
#pragma unroll
        for (int j = 0; j < 4; ++j) bf[j] = *(const short8*)(bufB + offB[j]);
        if (t + 3 < NT) stageA(t + 3);
        SBAR();
        PRIO(1);
#pragma unroll
        for (int i = 0; i < 4; ++i)
#pragma unroll
            for (int j = 0; j < 4; ++j)
                acc[i][j] = __builtin_amdgcn_mfma_f32_16x16x32_bf16(af[i], bf[j], acc[i][j], 0, 0, 0);
        PRIO(0);
#pragma unroll
        for (int i = 4; i < 8; ++i) af[i] = *(const short8*)(buf + offA[i]);
        if (t + 3 < NT) stageB(t + 3);
        SBAR();
        PRIO(1);
#pragma unroll
        for (int i = 4; i < 8; ++i)
#pragma unroll
            for (int j = 0; j < 4; ++j)
                acc[i][j] = __builtin_amdgcn_mfma_f32_16x16x32_bf16(af[i], bf[j], acc[i][j], 0, 0, 0);
        PRIO(0);
        if (t + 1 < NT) {
            if (t + 3 < NT)      { WAITVM(8); }
            else if (t + 2 < NT) { WAITVM(4); }
            else                 { WAITVM(0); }
            SBAR(); SCHED0();
        }
    }

#pragma unroll
    for (int i = 0; i < 8; ++i)
#pragma unroll
        for (int j = 0; j < 4; ++j) {
            const int r0 = row0 + wm * 128 + i * 16 + fq * 4;
            const int c  = col0 + wn * 64 + j * 16 + fr;
#pragma unroll
            for (int rr = 0; rr < 4; ++rr) {
                if (EPI == 0) Cb[(size_t)(r0 + rr) * D_DIM + c] = f2bf(acc[i][j][rr]);
                else          Cf[(size_t)(r0 + rr) * D_DIM + c] = acc[i][j][rr];
            }
        }
}

// ===========================================================================
// gemm_x3: split-precision GEMM (Ah@Wh + Ah@Wl + Al@Wh), 128x256 tile, BK=32,
// 512 thr, 3 bufs, vmcnt(6). EPI: 0 = hi/lo bf16 split out, 1 = f32 out,
// 2 = fused router-dot partials: Pd[(by*4+wn)*Ltot + l] = sum_c C[l,c]*E[l-1,c]
// where E = Eh+El (no C materialization).
// ===========================================================================
template<int EPI>
__global__ __launch_bounds__(512) void gemm_x3(const u16* __restrict__ Ah,
                                               const u16* __restrict__ Al,
                                               const u16* __restrict__ Wh,
                                               const u16* __restrict__ Wl,
                                               float* __restrict__ Cf,
                                               u16* __restrict__ Chi,
                                               u16* __restrict__ Clo,
                                               const u16* __restrict__ Eh,
                                               const u16* __restrict__ El,
                                               float* __restrict__ Pd) {
    constexpr int NT = 32;
    __shared__ u16 lds[3 * 24576];
    const int tid = threadIdx.x;
    const int lane = tid & 63, wid = tid >> 6;
    const int wm = wid >> 2, wn = wid & 3;
    const int fr = lane & 15, fq = lane >> 4;
    const int row0 = blockIdx.x * 128, col0 = blockIdx.y * 256;
    const int r0s = tid >> 2, c0s = tid & 3;

    int offA[4], offB[4];
#pragma unroll
    for (int i = 0; i < 4; ++i) {
        const int r = wm * 64 + i * 16 + fr;
        offA[i] = r * 64 + ((fq ^ ((r >> 1) & 3)) << 4);
    }
#pragma unroll
    for (int j = 0; j < 4; ++j) {
        const int r = wn * 64 + j * 16 + fr;
        offB[j] = r * 64 + ((fq ^ ((r >> 1) & 3)) << 4);
    }

    auto stageAhl = [&](int s) {
        char* base = (char*)lds + (s % 3) * 49152;
        const int r = r0s;
        const int c = c0s ^ ((r >> 1) & 3);
        const size_t g = (size_t)(row0 + r) * D_DIM + s * 32 + c * 8;
        GLOAD16(Ah + g, base + tid * 16);
        GLOAD16(Al + g, base + 8192 + tid * 16);
    };
    auto stageBh = [&](int s) {
        char* base = (char*)lds + (s % 3) * 49152 + 16384;
#pragma unroll
        for (int j = 0; j < 2; ++j) {
            const int r = j * 128 + r0s;
            const int c = c0s ^ ((r >> 1) & 3);
            GLOAD16(Wh + (size_t)(col0 + r) * D_DIM + s * 32 + c * 8,
                    base + j * 8192 + tid * 16);
        }
    };
    auto stageBl = [&](int s) {
        char* base = (char*)lds + (s % 3) * 49152 + 32768;
#pragma unroll
        for (int j = 0; j < 2; ++j) {
            const int r = j * 128 + r0s;
            const int c = c0s ^ ((r >> 1) & 3);
            GLOAD16(Wl + (size_t)(col0 + r) * D_DIM + s * 32 + c * 8,
                    base + j * 8192 + tid * 16);
        }
    };

    f32x4 acc[4][4];
#pragma unroll
    for (int i = 0; i < 4; ++i)
#pragma unroll
        for (int j = 0; j < 4; ++j) acc[i][j] = (f32x4){0.f, 0.f, 0.f, 0.f};

    stageAhl(0); stageBh(0); stageBl(0);
    stageAhl(1); stageBh(1); stageBl(1);
    WAITVM(6); SBAR(); SCHED0();

    for (int t = 0; t < NT; ++t) {
        const char* base = (const char*)lds + (t % 3) * 49152;
        short8 afh[4], afl[4], bfh[4], bfl[4];
#pragma unroll
        for (int i = 0; i < 4; ++i) afh[i] = *(const short8*)(base + offA[i]);
#pragma unroll
        for (int j = 0; j < 4; ++j) bfh[j] = *(const short8*)(base + 16384 + offB[j]);
        if (t + 2 < NT) stageBh(t + 2);
        SBAR();
        PRIO(1);
#pragma unroll
        for (int i = 0; i < 4; ++i)
#pragma unroll
            for (int j = 0; j < 4; ++j)
                acc[i][j] = __builtin_amdgcn_mfma_f32_16x16x32_bf16(afh[i], bfh[j], acc[i][j], 0, 0, 0);
        PRIO(0);
#pragma unroll
        for (int j = 0; j < 4; ++j) bfl[j] = *(const short8*)(base + 32768 + offB[j]);
        if (t + 2 < NT) stageBl(t + 2);
        SBAR();
        PRIO(1);
#pragma unroll
        for (int i = 0; i < 4; ++i)
#pragma unroll
            for (int j = 0; j < 4; ++j)
                acc[i][j] = __builtin_amdgcn_mfma_f32_16x16x32_bf16(afh[i], bfl[j], acc[i][j], 0, 0, 0);
        PRIO(0);
#pragma unroll
        for (int i = 0; i < 4; ++i) afl[i] = *(const short8*)(base + 8192 + offA[i]);
        if (t + 2 < NT) stageAhl(t + 2);
        SBAR();
        PRIO(1);
#pragma unroll
        for (int i = 0; i < 4; ++i)
#pragma unroll
            for (int j = 0; j < 4; ++j)
                acc[i][j] = __builtin_amdgcn_mfma_f32_16x16x32_bf16(afl[i], bfh[j], acc[i][j], 0, 0, 0);
        PRIO(0);
        if (t + 1 < NT) {
            if (t + 2 < NT) { WAITVM(6); }
            else            { WAITVM(0); }
            SBAR(); SCHED0();
        }
    }

    if (EPI == 2) {
        // fused router dot: per output row l, partial over this wave's 64 cols
        const int Ltot = gridDim.x * 128;
#pragma unroll
        for (int i = 0; i < 4; ++i)
#pragma unroll
            for (int rr = 0; rr < 4; ++rr) {
                const int r = row0 + wm * 64 + i * 16 + fq * 4 + rr;
                float s = 0.f;
#pragma unroll
                for (int j = 0; j < 4; ++j) {
                    const int c = col0 + wn * 64 + j * 16 + fr;
                    float e = 0.f;
                    if (r > 0) {
                        const size_t o = (size_t)(r - 1) * D_DIM + c;
                        e = bf2f(Eh[o]) + bf2f(El[o]);
                    }
                    s += acc[i][j][rr] * e;
                }
#pragma unroll
                for (int off = 1; off < 16; off <<= 1) s += __shfl_xor(s, off);
                if (fr == 0)
                    Pd[(size_t)(blockIdx.y * 4 + wn) * Ltot + r] = s;
            }
        return;
    }
#pragma unroll
    for (int i = 0; i < 4; ++i)
#pragma unroll
        for (int j = 0; j < 4; ++j) {
            const int r0 = row0 + wm * 64 + i * 16 + fq * 4;
            const int c  = col0 + wn * 64 + j * 16 + fr;
#pragma unroll
            for (int rr = 0; rr < 4; ++rr) {
                const float v = acc[i][j][rr];
                if (EPI == 0) {
                    const u16 h = f2bf(v);
                    Chi[(size_t)(r0 + rr) * D_DIM + c] = h;
                    Clo[(size_t)(r0 + rr) * D_DIM + c] = f2bf(v - bf2f(h));
                } else {
                    Cf[(size_t)(r0 + rr) * D_DIM + c] = v;
                }
            }
        }
}

// ===========================================================================
// norm2: fused dual-norm GEMM. A (128 rows) staged once; Bq, Bk (256 rows
// each); emits per-row sum-of-squares partials for q=A@Wq^T and k=A@Wk^T.
// 3 bufs x 40KB, counted vmcnt(5).
// ===========================================================================
__global__ __launch_bounds__(512) void norm2(const u16* __restrict__ A,
                                             const u16* __restrict__ Bq,
                                             const u16* __restrict__ Bk,
                                             float* __restrict__ Pq,
                                             float* __restrict__ Pk) {
    constexpr int NT = 32;
    __shared__ u16 lds[3 * 20480];          // per buf: A 8KB | Bq 16KB | Bk 16KB
    const int tid = threadIdx.x;
    const int lane = tid & 63, wid = tid >> 6;
    const int wm = wid >> 2, wn = wid & 3;
    const int fr = lane & 15, fq = lane >> 4;
    const int row0 = blockIdx.x * 128, col0 = blockIdx.y * 256;
    const int r0s = tid >> 2, c0s = tid & 3;

    int offA[4], offB[4];
#pragma unroll
    for (int i = 0; i < 4; ++i) {
        const int r = wm * 64 + i * 16 + fr;
        offA[i] = r * 64 + ((fq ^ ((r >> 1) & 3)) << 4);
    }
#pragma unroll
    for (int j = 0; j < 4; ++j) {
        const int r = wn * 64 + j * 16 + fr;
        offB[j] = r * 64 + ((fq ^ ((r >> 1) & 3)) << 4);
    }

    auto stageA = [&](int s) {
        char* base = (char*)lds + (s % 3) * 40960;
        const int r = r0s;
        const int c = c0s ^ ((r >> 1) & 3);
        GLOAD16(A + (size_t)(row0 + r) * D_DIM + s * 32 + c * 8, base + tid * 16);
    };
    auto stageBq = [&](int s) {
        char* base = (char*)lds + (s % 3) * 40960 + 8192;
#pragma unroll
        for (int j = 0; j < 2; ++j) {
            const int r = j * 128 + r0s;
            const int c = c0s ^ ((r >> 1) & 3);
            GLOAD16(Bq + (size_t)(col0 + r) * D_DIM + s * 32 + c * 8,
                    base + j * 8192 + tid * 16);
        }
    };
    auto stageBk = [&](int s) {
        char* base = (char*)lds + (s % 3) * 40960 + 24576;
#pragma unroll
        for (int j = 0; j < 2; ++j) {
            const int r = j * 128 + r0s;
            const int c = c0s ^ ((r >> 1) & 3);
            GLOAD16(Bk + (size_t)(col0 + r) * D_DIM + s * 32 + c * 8,
                    base + j * 8192 + tid * 16);
        }
    };

    f32x4 accq[4][4], acck[4][4];
#pragma unroll
    for (int i = 0; i < 4; ++i)
#pragma unroll
        for (int j = 0; j < 4; ++j) {
            accq[i][j] = (f32x4){0.f, 0.f, 0.f, 0.f};
            acck[i][j] = (f32x4){0.f, 0.f, 0.f, 0.f};
        }

    stageA(0); stageBq(0); stageBk(0);
    stageA(1); stageBq(1); stageBk(1);
    WAITVM(5); SBAR(); SCHED0();

    for (int t = 0; t < NT; ++t) {
        const char* base = (const char*)lds + (t % 3) * 40960;
        short8 af[4], bq[4], bk[4];
#pragma unroll
        for (int i = 0; i < 4; ++i) af[i] = *(const short8*)(base + offA[i]);
#pragma unroll
        for (int j = 0; j < 4; ++j) bq[j] = *(const short8*)(base + 8192 + offB[j]);
        if (t + 2 < NT) { stageA(t + 2); stageBq(t + 2); }
        SBAR();
        PRIO(1);
#pragma unroll
        for (int i = 0; i < 4; ++i)
#pragma unroll
            for (int j = 0; j < 4; ++j)
                accq[i][j] = __builtin_amdgcn_mfma_f32_16x16x32_bf16(af[i], bq[j], accq[i][j], 0, 0, 0);
        PRIO(0);
#pragma unroll
        for (int j = 0; j < 4; ++j) bk[j] = *(const short8*)(base + 24576 + offB[j]);
        if (t + 2 < NT) stageBk(t + 2);
        SBAR();
        PRIO(1);
#pragma unroll
        for (int i = 0; i < 4; ++i)
#pragma unroll
            for (int j = 0; j < 4; ++j)
                acck[i][j] = __builtin_amdgcn_mfma_f32_16x16x32_bf16(af[i], bk[j], acck[i][j], 0, 0, 0);
        PRIO(0);
        if (t + 1 < NT) {
            if (t + 2 < NT) { WAITVM(5); }
            else            { WAITVM(0); }
            SBAR(); SCHED0();
        }
    }

    const int Ltot = gridDim.x * 128;
#pragma unroll
    for (int i = 0; i < 4; ++i)
#pragma unroll
        for (int rr = 0; rr < 4; ++rr) {
            const int r = row0 + wm * 64 + i * 16 + fq * 4 + rr;
            float sq = 0.f, sk = 0.f;
#pragma unroll
            for (int j = 0; j < 4; ++j) {
                sq += accq[i][j][rr] * accq[i][j][rr];
                sk += acck[i][j][rr] * acck[i][j][rr];
            }
#pragma unroll
            for (int off = 1; off < 16; off <<= 1) {
                sq += __shfl_xor(sq, off);
                sk += __shfl_xor(sk, off);
            }
            if (fr == 0) {
                Pq[(size_t)(blockIdx.y * 4 + wn) * Ltot + r] = sq;
                Pk[(size_t)(blockIdx.y * 4 + wn) * Ltot + r] = sk;
            }
        }
}

// ---------------------------------------------------------------------------
// m97-style 128-tile plain bf16 GEMM for tiny D x D work
// ---------------------------------------------------------------------------
__global__ __launch_bounds__(256) void gemm_bf16_nt(const u16* __restrict__ A,
                                                    const u16* __restrict__ W,
                                                    float* __restrict__ C,
                                                    u16* __restrict__ Cbf) {
    __shared__ u16 lA[128 * 32];
    __shared__ u16 lB[128 * 32];
    const int tid  = threadIdx.x;
    const int lane = tid & 63, wid = tid >> 6;
    const int wy = wid & 1, wx = wid >> 1;
    const int fr = lane & 15, fq = lane >> 4;
    const int row0 = blockIdx.x * 128;
    const int col0 = blockIdx.y * 128;

    const int rS   = tid >> 2;
    const int subS = (tid & 3) ^ ((rS >> 1) & 3);
    const u16* gA = A + (size_t)(row0 + rS) * D_DIM + subS * 8;
    const u16* gB = W + (size_t)(col0 + rS) * D_DIM + subS * 8;
    char* lA0 = (char*)lA + tid * 16;
    char* lB0 = (char*)lB + tid * 16;
    const size_t rowStep = (size_t)64 * D_DIM;

    int offA[4], offB[4];
#pragma unroll
    for (int i = 0; i < 4; ++i) {
        const int ra = wy * 64 + i * 16 + fr;
        const int rb = wx * 64 + i * 16 + fr;
        offA[i] = ra * 64 + ((fq ^ ((ra >> 1) & 3)) << 4);
        offB[i] = rb * 64 + ((fq ^ ((rb >> 1) & 3)) << 4);
    }

    f32x4 acc[4][4];
#pragma unroll
    for (int i = 0; i < 4; ++i)
#pragma unroll
        for (int j = 0; j < 4; ++j) acc[i][j] = (f32x4){0.f, 0.f, 0.f, 0.f};

    for (int k0 = 0; k0 < D_DIM; k0 += 32) {
        __syncthreads();
        GLOAD16(gA + k0, lA0);
        GLOAD16(gA + k0 + rowStep, lA0 + 4096);
        GLOAD16(gB + k0, lB0);
        GLOAD16(gB + k0 + rowStep, lB0 + 4096);
        __syncthreads();
        short8 af[4], bf[4];
#pragma unroll
        for (int i = 0; i < 4; ++i) af[i] = *(const short8*)((const char*)lA + offA[i]);
#pragma unroll
        for (int j = 0; j < 4; ++j) bf[j] = *(const short8*)((const char*)lB + offB[j]);
#pragma unroll
        for (int i = 0; i < 4; ++i)
#pragma unroll
            for (int j = 0; j < 4; ++j)
                acc[i][j] = __builtin_amdgcn_mfma_f32_16x16x32_bf16(af[i], bf[j], acc[i][j], 0, 0, 0);
    }
#pragma unroll
    for (int i = 0; i < 4; ++i)
#pragma unroll
        for (int j = 0; j < 4; ++j) {
            const int r0 = row0 + wy * 64 + i * 16 + fq * 4;
            const int c  = col0 + wx * 64 + j * 16 + fr;
            if (Cbf) {
#pragma unroll
                for (int r = 0; r < 4; ++r)
                    Cbf[(size_t)(r0 + r) * D_DIM + c] = f2bf(acc[i][j][r]);
            } else {
#pragma unroll
                for (int r = 0; r < 4; ++r)
                    C[(size_t)(r0 + r) * D_DIM + c] = acc[i][j][r];
            }
        }
}

// ---------------------------------------------------------------------------
// small kernels
// ---------------------------------------------------------------------------
__global__ void split_bf16(const float* __restrict__ src, u16* __restrict__ hi,
                           u16* __restrict__ lo, int n4) {
    int i = blockIdx.x * 256 + threadIdx.x;
    if (i >= n4) return;
    float4 v = ((const float4*)src)[i];
    ushort4 h, l;
    h.x = f2bf(v.x); l.x = f2bf(v.x - bf2f(h.x));
    h.y = f2bf(v.y); l.y = f2bf(v.y - bf2f(h.y));
    h.z = f2bf(v.z); l.z = f2bf(v.z - bf2f(h.z));
    h.w = f2bf(v.w); l.w = f2bf(v.w - bf2f(h.w));
    ((ushort4*)hi)[i] = h;
    ((ushort4*)lo)[i] = l;
}

__global__ void conv_bf16(const float* __restrict__ src, u16* __restrict__ dst, int n4) {
    int i = blockIdx.x * 256 + threadIdx.x;
    if (i >= n4) return;
    float4 v = ((const float4*)src)[i];
    ushort4 o = {f2bf(v.x), f2bf(v.y), f2bf(v.z), f2bf(v.w)};
    ((ushort4*)dst)[i] = o;
}

__global__ __launch_bounds__(256) void transpose_split(const float* __restrict__ W,
                                                       u16* __restrict__ Th,
                                                       u16* __restrict__ Tl) {
    __shared__ float tile[32][33];
    const int e0 = blockIdx.x * 32, d0 = blockIdx.y * 32;
    const int tx = threadIdx.x & 31, ty = threadIdx.x >> 5;
#pragma unroll
    for (int i = 0; i < 32; i += 8)
        tile[ty + i][tx] = W[(size_t)(e0 + ty + i) * D_DIM + d0 + tx];
    __syncthreads();
#pragma unroll
    for (int i = 0; i < 32; i += 8) {
        float v = tile[tx][ty + i];
        u16 h = f2bf(v);
        Th[(size_t)(d0 + ty + i) * D_DIM + e0 + tx] = h;
        if (Tl) Tl[(size_t)(d0 + ty + i) * D_DIM + e0 + tx] = f2bf(v - bf2f(h));
    }
}

// combine fused-router partials -> p -> gates a, bs
__global__ void combine_router(const float* __restrict__ pd,
                               const float* __restrict__ pq,
                               const float* __restrict__ pk,
                               const int* __restrict__ cu, int nseq,
                               float* __restrict__ a, float* __restrict__ bs,
                               int L) {
    int l = blockIdx.x * 256 + threadIdx.x;
    if (l >= L) return;
    float dot = 0.f, q2 = 0.f, k2 = 0.f;
#pragma unroll
    for (int j = 0; j < 16; ++j) {
        dot += pd[(size_t)j * L + l];
        k2  += pk[(size_t)j * L + l];
        if (l > 0) q2 += pq[(size_t)j * L + l - 1];
    }
    float pv;
    if (l == 0) pv = 1.f;
    else {
        float dn = fmaxf(sqrtf(q2), 1e-12f) * fmaxf(sqrtf(k2), 1e-12f);
        pv = 0.5f * (1.f - dot / dn);
    }
    bool start = false;
    for (int s = 0; s < nseq; ++s) start = start || (cu[s] == l);
    if (start) pv = 1.f;
    bool mask = pv > 0.5f;
    float pc  = fminf(fmaxf(pv, 1e-4f), 1.f - 1e-4f);
    a[l]  = start ? 0.f : (mask ? (1.f - pc) : 1.f);
    bs[l] = mask ? pc : 0.f;
}

// ---------------------------------------------------------------------------
// scan (bf16 z storage, f32 running state)
// ---------------------------------------------------------------------------
__global__ __launch_bounds__(256) void scan_local(const float* __restrict__ a,
                                                  const float* __restrict__ bs,
                                                  u16* __restrict__ m,
                                                  float* __restrict__ P) {
    __shared__ float a_s[CL], b_s[CL];
    const int chunk = blockIdx.x;
    const int d     = blockIdx.y * 256 + threadIdx.x;
    const int l0    = chunk * CL;
    for (int i = threadIdx.x; i < CL; i += 256) { a_s[i] = a[l0 + i]; b_s[i] = bs[l0 + i]; }
    __syncthreads();
    if (blockIdx.y == 0 && threadIdx.x == 0) {
        float pp = 1.f;
        for (int i = 0; i < CL; ++i) { pp *= a_s[i]; P[l0 + i] = pp; }
    }
    float h = 0.f;
    u16* mp = m + (size_t)l0 * D_DIM + d;
    for (int i = 0; i < CL; ++i) {
        float mv = bf2f(mp[(size_t)i * D_DIM]);
        h = fmaf(a_s[i], h, b_s[i] * mv);
        mp[(size_t)i * D_DIM] = f2bf(h);
    }
}

__global__ void scan_carry(const u16* __restrict__ y, const float* __restrict__ P,
                           float* __restrict__ carry, int nchunks) {
    const int d = blockIdx.x * 256 + threadIdx.x;
    float H = 0.f;
    for (int c = 0; c < nchunks; ++c) {
        carry[(size_t)c * D_DIM + d] = H;
        const float Ac = P[c * CL + (CL - 1)];
        const float Bc = bf2f(y[((size_t)c * CL + (CL - 1)) * D_DIM + d]);
        H = fmaf(Ac, H, Bc);
    }
}

// final: out = z_local + P[l]*carry + r  (f32 out, 8 elems/thread)
__global__ void fixup_out(const u16* __restrict__ z, const float* __restrict__ P,
                          const float* __restrict__ carry, const u16* __restrict__ r,
                          float* __restrict__ out) {
    const size_t i8  = (size_t)blockIdx.x * 256 + threadIdx.x;
    const size_t idx = i8 * 8;
    const int l  = (int)(idx >> 10);
    const int dd = (int)(idx & 1023);
    const int c  = l >> 9;                    // CL = 512
    const float pl = P[l];
    short8 zv = *(const short8*)(z + idx);
    short8 rv = *(const short8*)(r + idx);
    const float4 c0 = *(const float4*)(carry + (size_t)c * D_DIM + dd);
    const float4 c1 = *(const float4*)(carry + (size_t)c * D_DIM + dd + 4);
    float4 o0, o1;
    o0.x = fmaf(pl, c0.x, bf2f((u16)zv[0])) + bf2f((u16)rv[0]);
    o0.y = fmaf(pl, c0.y, bf2f((u16)zv[1])) + bf2f((u16)rv[1]);
    o0.z = fmaf(pl, c0.z, bf2f((u16)zv[2])) + bf2f((u16)rv[2]);
    o0.w = fmaf(pl, c0.w, bf2f((u16)zv[3])) + bf2f((u16)rv[3]);
    o1.x = fmaf(pl, c1.x, bf2f((u16)zv[4])) + bf2f((u16)rv[4]);
    o1.y = fmaf(pl, c1.y, bf2f((u16)zv[5])) + bf2f((u16)rv[5]);
    o1.z = fmaf(pl, c1.z, bf2f((u16)zv[6])) + bf2f((u16)rv[6]);
    o1.w = fmaf(pl, c1.w, bf2f((u16)zv[7])) + bf2f((u16)rv[7]);
    *(float4*)(out + idx)     = o0;
    *(float4*)(out + idx + 4) = o1;
}

// ---------------------------------------------------------------------------
extern "C" void kernel_launch(void* const* d_in, const int* in_sizes, int n_in,
                              void* d_out, int out_size, void* d_ws, size_t ws_size,
                              hipStream_t stream) {
    const float* x  = (const float*)d_in[0];
    const float* Wq = (const float*)d_in[1];
    const float* Wk = (const float*)d_in[2];
    const float* Wr = (const float*)d_in[3];
    const float* We = (const float*)d_in[4];
    const float* Wm = (const float*)d_in[5];
    const float* Wd = (const float*)d_in[6];
    const int*   cu = (const int*)d_in[7];
    const int L    = in_sizes[0] / D_DIM;      // 32768
    const int nseq = in_sizes[7] - 1;          // 4

    const size_t LD2 = (size_t)L * D_DIM * 2;  // 64 MiB bf16 plane
    const size_t DD  = (size_t)D_DIM * D_DIM;
    const int nLD4 = L * D_DIM / 4;
    const int nDD4 = (int)(DD / 4);
    const int nchunks = L / CL;

    // ws: R1a x_hi -> z | R1b x_lo -> r | R2a enc_hi | R2b enc_lo | scalars
    char* ws = (char*)d_ws;
    u16*   xh   = (u16*)ws;
    u16*   xl   = (u16*)(ws + LD2);
    u16*   zbuf = (u16*)ws;
    u16*   rbuf = (u16*)(ws + LD2);
    u16*   ench = (u16*)(ws + 2 * LD2);
    u16*   encl = (u16*)(ws + 3 * LD2);
    float* av   = (float*)(ws + 4 * LD2);
    float* bs   = av + L;
    float* P    = bs + L;
    float* carry= P  + L;                      // [nchunks, D] = 256 KB

    // d_out scratch (all dead before fixup_out writes out):
    char* dob = (char*)d_out;
    u16* Weh   = (u16*)dob;
    u16* Wel   = (u16*)(dob + (2u << 20));
    u16* WqTh  = (u16*)(dob + (4u << 20));
    u16* WqTl  = (u16*)(dob + (6u << 20));
    u16* WkTh  = (u16*)(dob + (8u << 20));
    u16* WkTl  = (u16*)(dob + (10u << 20));
    float* Mf  = (float*)(dob + (12u << 20));
    u16* Mh    = (u16*)(dob + (16u << 20));
    u16* Ml    = (u16*)(dob + (18u << 20));
    u16* Wqb   = (u16*)(dob + (20u << 20));
    u16* Wkb   = (u16*)(dob + (22u << 20));
    u16* WmTb  = (u16*)(dob + (24u << 20));
    u16* WrTb  = (u16*)(dob + (26u << 20));
    u16* Wdb   = (u16*)(dob + (28u << 20));
    u16* Wdmb  = (u16*)(dob + (30u << 20));
    u16* Wdrb  = (u16*)(dob + (32u << 20));
    float* partdot = (float*)(dob + (34u << 20));   // [16][L] = 2 MB
    float* partnq  = (float*)(dob + (36u << 20));
    float* partnk  = (float*)(dob + (38u << 20));
    float* out = (float*)d_out;

    dim3 gX3L(L / 128, D_DIM / 256);           // (256, 4)
    dim3 gX3D(D_DIM / 128, D_DIM / 256);       // (8, 4)
    dim3 g256(L / 256, D_DIM / 256);           // (128, 4)
    dim3 gD(D_DIM / 128, D_DIM / 128);         // (8, 8)
    dim3 gT(D_DIM / 32, D_DIM / 32);

    // 1. splits
    split_bf16<<<(nLD4 + 255) / 256, 256, 0, stream>>>(x, xh, xl, nLD4);
    split_bf16<<<(nDD4 + 255) / 256, 256, 0, stream>>>(We, Weh, Wel, nDD4);
    // 2. enc (x3) -> hi/lo planes
    gemm_x3<0><<<gX3L, 512, 0, stream>>>(xh, xl, Weh, Wel, nullptr, ench, encl,
                                         nullptr, nullptr, nullptr);
    // 3. M = Wq^T @ Wk (x3)
    transpose_split<<<gT, 256, 0, stream>>>(Wq, WqTh, WqTl);
    transpose_split<<<gT, 256, 0, stream>>>(Wk, WkTh, WkTl);
    gemm_x3<1><<<gX3D, 512, 0, stream>>>(WqTh, WqTl, WkTh, WkTl, Mf, nullptr, nullptr,
                                         nullptr, nullptr, nullptr);
    split_bf16<<<(nDD4 + 255) / 256, 256, 0, stream>>>(Mf, Mh, Ml, nDD4);
    // 4. fused t-GEMM + router dot partials (t never materialized)
    gemm_x3<2><<<gX3L, 512, 0, stream>>>(ench, encl, Mh, Ml, nullptr, nullptr, nullptr,
                                         ench, encl, partdot);
    // 5. fused q,k norm partials
    conv_bf16<<<(nDD4 + 255) / 256, 256, 0, stream>>>(Wq, Wqb, nDD4);
    conv_bf16<<<(nDD4 + 255) / 256, 256, 0, stream>>>(Wk, Wkb, nDD4);
    norm2<<<gX3L, 512, 0, stream>>>(ench, Wqb, Wkb, partnq, partnk);
    // 6. combine partials -> p -> gates
    combine_router<<<(L + 255) / 256, 256, 0, stream>>>(partdot, partnq, partnk,
                                                        cu, nseq, av, bs, L);
    // 7. Wdm = Wd@Wm, Wdr = Wd@Wr (tiny)
    conv_bf16<<<(nDD4 + 255) / 256, 256, 0, stream>>>(Wd, Wdb, nDD4);
    transpose_split<<<gT, 256, 0, stream>>>(Wm, WmTb, nullptr);
    transpose_split<<<gT, 256, 0, stream>>>(Wr, WrTb, nullptr);
    gemm_bf16_nt<<<gD, 256, 0, stream>>>(Wdb, WmTb, nullptr, Wdmb);
    gemm_bf16_nt<<<gD, 256, 0, stream>>>(Wdb, WrTb, nullptr, Wdrb);
    // 8. z = enc @ Wdm^T (x planes dead); r = enc @ Wdr^T
    gemm256<0><<<g256, 512, 0, stream>>>(ench, Wdmb, nullptr, zbuf);
    gemm256<0><<<g256, 512, 0, stream>>>(ench, Wdrb, nullptr, rbuf);
    // 9. scan over z (decode-commuted), then out = y + r (f32)
    dim3 gsl(nchunks, D_DIM / 256);
    scan_local<<<gsl, 256, 0, stream>>>(av, bs, zbuf, P);
    scan_carry<<<D_DIM / 256, 256, 0, stream>>>(zbuf, P, carry, nchunks);
    fixup_out<<<(size_t)L * D_DIM / 8 / 256, 256, 0, stream>>>(zbuf, P, carry, rbuf, out);
}

// Round 7
// 916.267 us; speedup vs baseline: 5.6622x; 1.0937x over previous
//
#include <hip/hip_runtime.h>
#include <math.h>

#define D_DIM 1024
#define CL 512   // scan chunk length

typedef __attribute__((ext_vector_type(8))) short short8;
typedef __attribute__((ext_vector_type(4))) float f32x4;
typedef unsigned short u16;

__device__ __forceinline__ u16 f2bf(float f) {
    unsigned int u = __float_as_uint(f);
    u += 0x7fff + ((u >> 16) & 1);          // round-to-nearest-even
    return (u16)(u >> 16);
}
__device__ __forceinline__ float bf2f(u16 h) {
    return __uint_as_float((unsigned int)h << 16);
}

#define GLOAD16(g, l) __builtin_amdgcn_global_load_lds(                      \
        (const __attribute__((address_space(1))) void*)(g),                  \
        (__attribute__((address_space(3))) void*)(l), 16, 0, 0)
#define SBAR()   __builtin_amdgcn_s_barrier()
#define SCHED0() __builtin_amdgcn_sched_barrier(0)
#define PRIO(x)  __builtin_amdgcn_s_setprio(x)
#define WAITVM(N) asm volatile("s_waitcnt vmcnt(" #N ")" ::: "memory")

// LDS swizzle (verified conflicts==0): (row r, 16B-chunk c) at byte
//   r*64 + (c ^ ((r>>1)&3))*16;  staging pre-inverse-swizzles the global src.

// ===========================================================================
// gemm256: plain bf16 GEMM, 256x256 tile, BK=32, 512 thr, 4 LDS bufs,
// counted-vmcnt pipeline. EPI: 0 = bf16 C, 1 = f32 C,
// 3 = fused scan-out: Cf = acc + bf2f(zin) + Pv[row]*carry[chunk,col] (f32).
// ===========================================================================
template<int EPI>
__global__ __launch_bounds__(512) void gemm256(const u16* __restrict__ A1,
                                               const u16* __restrict__ W1,
                                               float* __restrict__ Cf,
                                               u16* __restrict__ Cb,
                                               const u16* __restrict__ zin,
                                               const float* __restrict__ Pv,
                                               const float* __restrict__ carry) {
    constexpr int NT = 32;
    __shared__ u16 lds[4 * 16384];
    const int tid = threadIdx.x;
    const int lane = tid & 63, wid = tid >> 6;
    const int wm = wid >> 2, wn = wid & 3;
    const int fr = lane & 15, fq = lane >> 4;
    const int row0 = blockIdx.x * 256, col0 = blockIdx.y * 256;
    const int r0s = tid >> 2, c0s = tid & 3;

    int offA[8], offB[4];
#pragma unroll
    for (int i = 0; i < 8; ++i) {
        const int r = wm * 128 + i * 16 + fr;
        offA[i] = r * 64 + ((fq ^ ((r >> 1) & 3)) << 4);
    }
#pragma unroll
    for (int j = 0; j < 4; ++j) {
        const int r = wn * 64 + j * 16 + fr;
        offB[j] = r * 64 + ((fq ^ ((r >> 1) & 3)) << 4);
    }

    auto stageA = [&](int s) {
        const int k0 = s * 32;
        char* dst = (char*)lds + (s & 3) * 32768;
#pragma unroll
        for (int j = 0; j < 2; ++j) {
            const int r = j * 128 + r0s;
            const int c = c0s ^ ((r >> 1) & 3);
            GLOAD16(A1 + (size_t)(row0 + r) * D_DIM + k0 + c * 8,
                    dst + j * 8192 + tid * 16);
        }
    };
    auto stageB = [&](int s) {
        const int k0 = s * 32;
        char* dst = (char*)lds + (s & 3) * 32768 + 16384;
#pragma unroll
        for (int j = 0; j < 2; ++j) {
            const int r = j * 128 + r0s;
            const int c = c0s ^ ((r >> 1) & 3);
            GLOAD16(W1 + (size_t)(col0 + r) * D_DIM + k0 + c * 8,
                    dst + j * 8192 + tid * 16);
        }
    };

    f32x4 acc[8][4];
#pragma unroll
    for (int i = 0; i < 8; ++i)
#pragma unroll
        for (int j = 0; j < 4; ++j) acc[i][j] = (f32x4){0.f, 0.f, 0.f, 0.f};

    stageA(0); stageB(0); stageA(1); stageB(1); stageA(2); stageB(2);
    WAITVM(8); SBAR(); SCHED0();

    for (int t = 0; t < NT; ++t) {
        const char* buf  = (const char*)lds + (t & 3) * 32768;
        const char* bufB = buf + 16384;
        short8 af[8], bf[4];
#pragma unroll
        for (int i = 0; i < 4; ++i) af[i] = *(const short8*)(buf + offA[i]);
#pragma unroll
        for (int j = 0; j < 4; ++j) bf[j] = *(const short8*)(bufB + offB[j]);
        if (t + 3 < NT) stageA(t + 3);
        SBAR();
        PRIO(1);
#pragma unroll
        for (int i = 0; i < 4; ++i)
#pragma unroll
            for (int j = 0; j < 4; ++j)
                acc[i][j] = __builtin_amdgcn_mfma_f32_16x16x32_bf16(af[i], bf[j], acc[i][j], 0, 0, 0);
        PRIO(0);
#pragma unroll
        for (int i = 4; i < 8; ++i) af[i] = *(const short8*)(buf + offA[i]);
        if (t + 3 < NT) stageB(t + 3);
        SBAR();
        PRIO(1);
#pragma unroll
        for (int i = 4; i < 8; ++i)
#pragma unroll
            for (int j = 0; j < 4; ++j)
                acc[i][j] = __builtin_amdgcn_mfma_f32_16x16x32_bf16(af[i], bf[j], acc[i][j], 0, 0, 0);
        PRIO(0);
        if (t + 1 < NT) {
            if (t + 3 < NT)      { WAITVM(8); }
            else if (t + 2 < NT) { WAITVM(4); }
            else                 { WAITVM(0); }
            SBAR(); SCHED0();
        }
    }

#pragma unroll
    for (int i = 0; i < 8; ++i)
#pragma unroll
        for (int j = 0; j < 4; ++j) {
            const int r0 = row0 + wm * 128 + i * 16 + fq * 4;
            const int c  = col0 + wn * 64 + j * 16 + fr;
#pragma unroll
            for (int rr = 0; rr < 4; ++rr) {
                if (EPI == 0) Cb[(size_t)(r0 + rr) * D_DIM + c] = f2bf(acc[i][j][rr]);
                else if (EPI == 1) Cf[(size_t)(r0 + rr) * D_DIM + c] = acc[i][j][rr];
                else {
                    const int r = r0 + rr;
                    const float pl = Pv[r];
                    const float cv = carry[(size_t)(r >> 9) * D_DIM + c];
                    const float zv = bf2f(zin[(size_t)r * D_DIM + c]);
                    Cf[(size_t)r * D_DIM + c] = acc[i][j][rr] + fmaf(pl, cv, zv);
                }
            }
        }
}

// ===========================================================================
// gemm_x3: split-precision GEMM (Ah@Wh + Ah@Wl + Al@Wh), 128x256 tile, BK=32,
// 512 thr, 3 bufs, vmcnt(6). EPI: 0 = hi/lo bf16 split out, 1 = f32 out,
// 2 = fused router-dot partials via LDS redistribution:
//     Pd[(by*4+q)*Ltot + l] = sum over 64 cols of C[l,c]*(Eh+El)[l-1,c].
// ===========================================================================
template<int EPI>
__global__ __launch_bounds__(512) void gemm_x3(const u16* __restrict__ Ah,
                                               const u16* __restrict__ Al,
                                               const u16* __restrict__ Wh,
                                               const u16* __restrict__ Wl,
                                               float* __restrict__ Cf,
                                               u16* __restrict__ Chi,
                                               u16* __restrict__ Clo,
                                               const u16* __restrict__ Eh,
                                               const u16* __restrict__ El,
                                               float* __restrict__ Pd) {
    constexpr int NT = 32;
    __shared__ u16 lds[3 * 24576];           // 147456 B; reused as lt[] in EPI=2
    const int tid = threadIdx.x;
    const int lane = tid & 63, wid = tid >> 6;
    const int wm = wid >> 2, wn = wid & 3;
    const int fr = lane & 15, fq = lane >> 4;
    const int row0 = blockIdx.x * 128, col0 = blockIdx.y * 256;
    const int r0s = tid >> 2, c0s = tid & 3;

    int offA[4], offB[4];
#pragma unroll
    for (int i = 0; i < 4; ++i) {
        const int r = wm * 64 + i * 16 + fr;
        offA[i] = r * 64 + ((fq ^ ((r >> 1) & 3)) << 4);
    }
#pragma unroll
    for (int j = 0; j < 4; ++j) {
        const int r = wn * 64 + j * 16 + fr;
        offB[j] = r * 64 + ((fq ^ ((r >> 1) & 3)) << 4);
    }

    auto stageAhl = [&](int s) {
        char* base = (char*)lds + (s % 3) * 49152;
        const int r = r0s;
        const int c = c0s ^ ((r >> 1) & 3);
        const size_t g = (size_t)(row0 + r) * D_DIM + s * 32 + c * 8;
        GLOAD16(Ah + g, base + tid * 16);
        GLOAD16(Al + g, base + 8192 + tid * 16);
    };
    auto stageBh = [&](int s) {
        char* base = (char*)lds + (s % 3) * 49152 + 16384;
#pragma unroll
        for (int j = 0; j < 2; ++j) {
            const int r = j * 128 + r0s;
            const int c = c0s ^ ((r >> 1) & 3);
            GLOAD16(Wh + (size_t)(col0 + r) * D_DIM + s * 32 + c * 8,
                    base + j * 8192 + tid * 16);
        }
    };
    auto stageBl = [&](int s) {
        char* base = (char*)lds + (s % 3) * 49152 + 32768;
#pragma unroll
        for (int j = 0; j < 2; ++j) {
            const int r = j * 128 + r0s;
            const int c = c0s ^ ((r >> 1) & 3);
            GLOAD16(Wl + (size_t)(col0 + r) * D_DIM + s * 32 + c * 8,
                    base + j * 8192 + tid * 16);
        }
    };

    f32x4 acc[4][4];
#pragma unroll
    for (int i = 0; i < 4; ++i)
#pragma unroll
        for (int j = 0; j < 4; ++j) acc[i][j] = (f32x4){0.f, 0.f, 0.f, 0.f};

    stageAhl(0); stageBh(0); stageBl(0);
    stageAhl(1); stageBh(1); stageBl(1);
    WAITVM(6); SBAR(); SCHED0();

    for (int t = 0; t < NT; ++t) {
        const char* base = (const char*)lds + (t % 3) * 49152;
        short8 afh[4], afl[4], bfh[4], bfl[4];
#pragma unroll
        for (int i = 0; i < 4; ++i) afh[i] = *(const short8*)(base + offA[i]);
#pragma unroll
        for (int j = 0; j < 4; ++j) bfh[j] = *(const short8*)(base + 16384 + offB[j]);
        if (t + 2 < NT) stageBh(t + 2);
        SBAR();
        PRIO(1);
#pragma unroll
        for (int i = 0; i < 4; ++i)
#pragma unroll
            for (int j = 0; j < 4; ++j)
                acc[i][j] = __builtin_amdgcn_mfma_f32_16x16x32_bf16(afh[i], bfh[j], acc[i][j], 0, 0, 0);
        PRIO(0);
#pragma unroll
        for (int j = 0; j < 4; ++j) bfl[j] = *(const short8*)(base + 32768 + offB[j]);
        if (t + 2 < NT) stageBl(t + 2);
        SBAR();
        PRIO(1);
#pragma unroll
        for (int i = 0; i < 4; ++i)
#pragma unroll
            for (int j = 0; j < 4; ++j)
                acc[i][j] = __builtin_amdgcn_mfma_f32_16x16x32_bf16(afh[i], bfl[j], acc[i][j], 0, 0, 0);
        PRIO(0);
#pragma unroll
        for (int i = 0; i < 4; ++i) afl[i] = *(const short8*)(base + 8192 + offA[i]);
        if (t + 2 < NT) stageAhl(t + 2);
        SBAR();
        PRIO(1);
#pragma unroll
        for (int i = 0; i < 4; ++i)
#pragma unroll
            for (int j = 0; j < 4; ++j)
                acc[i][j] = __builtin_amdgcn_mfma_f32_16x16x32_bf16(afl[i], bfh[j], acc[i][j], 0, 0, 0);
        PRIO(0);
        if (t + 1 < NT) {
            if (t + 2 < NT) { WAITVM(6); }
            else            { WAITVM(0); }
            SBAR(); SCHED0();
        }
    }

    if (EPI == 2) {
        // redistribute t through LDS (staging bufs dead), then coalesced E reads
        __syncthreads();
        float* lt = (float*)lds;             // [128][260] = 133120 B
#pragma unroll
        for (int i = 0; i < 4; ++i)
#pragma unroll
            for (int j = 0; j < 4; ++j) {
                const int rl = wm * 64 + i * 16 + fq * 4;
                const int cl = wn * 64 + j * 16 + fr;
#pragma unroll
                for (int rr = 0; rr < 4; ++rr)
                    lt[(rl + rr) * 260 + cl] = acc[i][j][rr];
            }
        __syncthreads();
        const int row = tid >> 2, q = tid & 3;
        const int rg  = row0 + row;
        float s = 0.f;
        if (rg > 0) {
            const u16* ehp = Eh + (size_t)(rg - 1) * D_DIM + col0 + q * 64;
            const u16* elp = El + (size_t)(rg - 1) * D_DIM + col0 + q * 64;
            const float* ltp = lt + row * 260 + q * 64;
#pragma unroll
            for (int k8 = 0; k8 < 8; ++k8) {
                short8 hv = *(const short8*)(ehp + k8 * 8);
                short8 lv = *(const short8*)(elp + k8 * 8);
#pragma unroll
                for (int e = 0; e < 8; ++e) {
                    const float ev = bf2f((u16)hv[e]) + bf2f((u16)lv[e]);
                    s = fmaf(ltp[k8 * 8 + e], ev, s);
                }
            }
        }
        Pd[(size_t)(blockIdx.y * 4 + q) * (gridDim.x * 128) + rg] = s;
        return;
    }
#pragma unroll
    for (int i = 0; i < 4; ++i)
#pragma unroll
        for (int j = 0; j < 4; ++j) {
            const int r0 = row0 + wm * 64 + i * 16 + fq * 4;
            const int c  = col0 + wn * 64 + j * 16 + fr;
#pragma unroll
            for (int rr = 0; rr < 4; ++rr) {
                const float v = acc[i][j][rr];
                if (EPI == 0) {
                    const u16 h = f2bf(v);
                    Chi[(size_t)(r0 + rr) * D_DIM + c] = h;
                    Clo[(size_t)(r0 + rr) * D_DIM + c] = f2bf(v - bf2f(h));
                } else {
                    Cf[(size_t)(r0 + rr) * D_DIM + c] = v;
                }
            }
        }
}

// ===========================================================================
// norm2: fused dual-norm GEMM (as round 6, unchanged).
// ===========================================================================
__global__ __launch_bounds__(512) void norm2(const u16* __restrict__ A,
                                             const u16* __restrict__ Bq,
                                             const u16* __restrict__ Bk,
                                             float* __restrict__ Pq,
                                             float* __restrict__ Pk) {
    constexpr int NT = 32;
    __shared__ u16 lds[3 * 20480];
    const int tid = threadIdx.x;
    const int lane = tid & 63, wid = tid >> 6;
    const int wm = wid >> 2, wn = wid & 3;
    const int fr = lane & 15, fq = lane >> 4;
    const int row0 = blockIdx.x * 128, col0 = blockIdx.y * 256;
    const int r0s = tid >> 2, c0s = tid & 3;

    int offA[4], offB[4];
#pragma unroll
    for (int i = 0; i < 4; ++i) {
        const int r = wm * 64 + i * 16 + fr;
        offA[i] = r * 64 + ((fq ^ ((r >> 1) & 3)) << 4);
    }
#pragma unroll
    for (int j = 0; j < 4; ++j) {
        const int r = wn * 64 + j * 16 + fr;
        offB[j] = r * 64 + ((fq ^ ((r >> 1) & 3)) << 4);
    }

    auto stageA = [&](int s) {
        char* base = (char*)lds + (s % 3) * 40960;
        const int r = r0s;
        const int c = c0s ^ ((r >> 1) & 3);
        GLOAD16(A + (size_t)(row0 + r) * D_DIM + s * 32 + c * 8, base + tid * 16);
    };
    auto stageBq = [&](int s) {
        char* base = (char*)lds + (s % 3) * 40960 + 8192;
#pragma unroll
        for (int j = 0; j < 2; ++j) {
            const int r = j * 128 + r0s;
            const int c = c0s ^ ((r >> 1) & 3);
            GLOAD16(Bq + (size_t)(col0 + r) * D_DIM + s * 32 + c * 8,
                    base + j * 8192 + tid * 16);
        }
    };
    auto stageBk = [&](int s) {
        char* base = (char*)lds + (s % 3) * 40960 + 24576;
#pragma unroll
        for (int j = 0; j < 2; ++j) {
            const int r = j * 128 + r0s;
            const int c = c0s ^ ((r >> 1) & 3);
            GLOAD16(Bk + (size_t)(col0 + r) * D_DIM + s * 32 + c * 8,
                    base + j * 8192 + tid * 16);
        }
    };

    f32x4 accq[4][4], acck[4][4];
#pragma unroll
    for (int i = 0; i < 4; ++i)
#pragma unroll
        for (int j = 0; j < 4; ++j) {
            accq[i][j] = (f32x4){0.f, 0.f, 0.f, 0.f};
            acck[i][j] = (f32x4){0.f, 0.f, 0.f, 0.f};
        }

    stageA(0); stageBq(0); stageBk(0);
    stageA(1); stageBq(1); stageBk(1);
    WAITVM(5); SBAR(); SCHED0();

    for (int t = 0; t < NT; ++t) {
        const char* base = (const char*)lds + (t % 3) * 40960;
        short8 af[4], bq[4], bk[4];
#pragma unroll
        for (int i = 0; i < 4; ++i) af[i] = *(const short8*)(base + offA[i]);
#pragma unroll
        for (int j = 0; j < 4; ++j) bq[j] = *(const short8*)(base + 8192 + offB[j]);
        if (t + 2 < NT) { stageA(t + 2); stageBq(t + 2); }
        SBAR();
        PRIO(1);
#pragma unroll
        for (int i = 0; i < 4; ++i)
#pragma unroll
            for (int j = 0; j < 4; ++j)
                accq[i][j] = __builtin_amdgcn_mfma_f32_16x16x32_bf16(af[i], bq[j], accq[i][j], 0, 0, 0);
        PRIO(0);
#pragma unroll
        for (int j = 0; j < 4; ++j) bk[j] = *(const short8*)(base + 24576 + offB[j]);
        if (t + 2 < NT) stageBk(t + 2);
        SBAR();
        PRIO(1);
#pragma unroll
        for (int i = 0; i < 4; ++i)
#pragma unroll
            for (int j = 0; j < 4; ++j)
                acck[i][j] = __builtin_amdgcn_mfma_f32_16x16x32_bf16(af[i], bk[j], acck[i][j], 0, 0, 0);
        PRIO(0);
        if (t + 1 < NT) {
            if (t + 2 < NT) { WAITVM(5); }
            else            { WAITVM(0); }
            SBAR(); SCHED0();
        }
    }

    const int Ltot = gridDim.x * 128;
#pragma unroll
    for (int i = 0; i < 4; ++i)
#pragma unroll
        for (int rr = 0; rr < 4; ++rr) {
            const int r = row0 + wm * 64 + i * 16 + fq * 4 + rr;
            float sq = 0.f, sk = 0.f;
#pragma unroll
            for (int j = 0; j < 4; ++j) {
                sq += accq[i][j][rr] * accq[i][j][rr];
                sk += acck[i][j][rr] * acck[i][j][rr];
            }
#pragma unroll
            for (int off = 1; off < 16; off <<= 1) {
                sq += __shfl_xor(sq, off);
                sk += __shfl_xor(sk, off);
            }
            if (fr == 0) {
                Pq[(size_t)(blockIdx.y * 4 + wn) * Ltot + r] = sq;
                Pk[(size_t)(blockIdx.y * 4 + wn) * Ltot + r] = sk;
            }
        }
}

// ---------------------------------------------------------------------------
// m97-style 128-tile plain bf16 GEMM for tiny D x D work
// ---------------------------------------------------------------------------
__global__ __launch_bounds__(256) void gemm_bf16_nt(const u16* __restrict__ A,
                                                    const u16* __restrict__ W,
                                                    float* __restrict__ C,
                                                    u16* __restrict__ Cbf) {
    __shared__ u16 lA[128 * 32];
    __shared__ u16 lB[128 * 32];
    const int tid  = threadIdx.x;
    const int lane = tid & 63, wid = tid >> 6;
    const int wy = wid & 1, wx = wid >> 1;
    const int fr = lane & 15, fq = lane >> 4;
    const int row0 = blockIdx.x * 128;
    const int col0 = blockIdx.y * 128;

    const int rS   = tid >> 2;
    const int subS = (tid & 3) ^ ((rS >> 1) & 3);
    const u16* gA = A + (size_t)(row0 + rS) * D_DIM + subS * 8;
    const u16* gB = W + (size_t)(col0 + rS) * D_DIM + subS * 8;
    char* lA0 = (char*)lA + tid * 16;
    char* lB0 = (char*)lB + tid * 16;
    const size_t rowStep = (size_t)64 * D_DIM;

    int offA[4], offB[4];
#pragma unroll
    for (int i = 0; i < 4; ++i) {
        const int ra = wy * 64 + i * 16 + fr;
        const int rb = wx * 64 + i * 16 + fr;
        offA[i] = ra * 64 + ((fq ^ ((ra >> 1) & 3)) << 4);
        offB[i] = rb * 64 + ((fq ^ ((rb >> 1) & 3)) << 4);
    }

    f32x4 acc[4][4];
#pragma unroll
    for (int i = 0; i < 4; ++i)
#pragma unroll
        for (int j = 0; j < 4; ++j) acc[i][j] = (f32x4){0.f, 0.f, 0.f, 0.f};

    for (int k0 = 0; k0 < D_DIM; k0 += 32) {
        __syncthreads();
        GLOAD16(gA + k0, lA0);
        GLOAD16(gA + k0 + rowStep, lA0 + 4096);
        GLOAD16(gB + k0, lB0);
        GLOAD16(gB + k0 + rowStep, lB0 + 4096);
        __syncthreads();
        short8 af[4], bf[4];
#pragma unroll
        for (int i = 0; i < 4; ++i) af[i] = *(const short8*)((const char*)lA + offA[i]);
#pragma unroll
        for (int j = 0; j < 4; ++j) bf[j] = *(const short8*)((const char*)lB + offB[j]);
#pragma unroll
        for (int i = 0; i < 4; ++i)
#pragma unroll
            for (int j = 0; j < 4; ++j)
                acc[i][j] = __builtin_amdgcn_mfma_f32_16x16x32_bf16(af[i], bf[j], acc[i][j], 0, 0, 0);
    }
#pragma unroll
    for (int i = 0; i < 4; ++i)
#pragma unroll
        for (int j = 0; j < 4; ++j) {
            const int r0 = row0 + wy * 64 + i * 16 + fq * 4;
            const int c  = col0 + wx * 64 + j * 16 + fr;
            if (Cbf) {
#pragma unroll
                for (int r = 0; r < 4; ++r)
                    Cbf[(size_t)(r0 + r) * D_DIM + c] = f2bf(acc[i][j][r]);
            } else {
#pragma unroll
                for (int r = 0; r < 4; ++r)
                    C[(size_t)(r0 + r) * D_DIM + c] = acc[i][j][r];
            }
        }
}

// ---------------------------------------------------------------------------
// small kernels
// ---------------------------------------------------------------------------
__global__ void split_bf16(const float* __restrict__ src, u16* __restrict__ hi,
                           u16* __restrict__ lo, int n4) {
    int i = blockIdx.x * 256 + threadIdx.x;
    if (i >= n4) return;
    float4 v = ((const float4*)src)[i];
    ushort4 h, l;
    h.x = f2bf(v.x); l.x = f2bf(v.x - bf2f(h.x));
    h.y = f2bf(v.y); l.y = f2bf(v.y - bf2f(h.y));
    h.z = f2bf(v.z); l.z = f2bf(v.z - bf2f(h.z));
    h.w = f2bf(v.w); l.w = f2bf(v.w - bf2f(h.w));
    ((ushort4*)hi)[i] = h;
    ((ushort4*)lo)[i] = l;
}

__global__ void conv_bf16(const float* __restrict__ src, u16* __restrict__ dst, int n4) {
    int i = blockIdx.x * 256 + threadIdx.x;
    if (i >= n4) return;
    float4 v = ((const float4*)src)[i];
    ushort4 o = {f2bf(v.x), f2bf(v.y), f2bf(v.z), f2bf(v.w)};
    ((ushort4*)dst)[i] = o;
}

__global__ __launch_bounds__(256) void transpose_split(const float* __restrict__ W,
                                                       u16* __restrict__ Th,
                                                       u16* __restrict__ Tl) {
    __shared__ float tile[32][33];
    const int e0 = blockIdx.x * 32, d0 = blockIdx.y * 32;
    const int tx = threadIdx.x & 31, ty = threadIdx.x >> 5;
#pragma unroll
    for (int i = 0; i < 32; i += 8)
        tile[ty + i][tx] = W[(size_t)(e0 + ty + i) * D_DIM + d0 + tx];
    __syncthreads();
#pragma unroll
    for (int i = 0; i < 32; i += 8) {
        float v = tile[tx][ty + i];
        u16 h = f2bf(v);
        Th[(size_t)(d0 + ty + i) * D_DIM + e0 + tx] = h;
        if (Tl) Tl[(size_t)(d0 + ty + i) * D_DIM + e0 + tx] = f2bf(v - bf2f(h));
    }
}

// combine fused-router partials -> p -> gates a, bs
__global__ void combine_router(const float* __restrict__ pd,
                               const float* __restrict__ pq,
                               const float* __restrict__ pk,
                               const int* __restrict__ cu, int nseq,
                               float* __restrict__ a, float* __restrict__ bs,
                               int L) {
    int l = blockIdx.x * 256 + threadIdx.x;
    if (l >= L) return;
    float dot = 0.f, q2 = 0.f, k2 = 0.f;
#pragma unroll
    for (int j = 0; j < 16; ++j) {
        dot += pd[(size_t)j * L + l];
        k2  += pk[(size_t)j * L + l];
        if (l > 0) q2 += pq[(size_t)j * L + l - 1];
    }
    float pv;
    if (l == 0) pv = 1.f;
    else {
        float dn = fmaxf(sqrtf(q2), 1e-12f) * fmaxf(sqrtf(k2), 1e-12f);
        pv = 0.5f * (1.f - dot / dn);
    }
    bool start = false;
    for (int s = 0; s < nseq; ++s) start = start || (cu[s] == l);
    if (start) pv = 1.f;
    bool mask = pv > 0.5f;
    float pc  = fminf(fmaxf(pv, 1e-4f), 1.f - 1e-4f);
    a[l]  = start ? 0.f : (mask ? (1.f - pc) : 1.f);
    bs[l] = mask ? pc : 0.f;
}

// ---------------------------------------------------------------------------
// scan (bf16 z storage, f32 running state)
// ---------------------------------------------------------------------------
__global__ __launch_bounds__(256) void scan_local(const float* __restrict__ a,
                                                  const float* __restrict__ bs,
                                                  u16* __restrict__ m,
                                                  float* __restrict__ P) {
    __shared__ float a_s[CL], b_s[CL];
    const int chunk = blockIdx.x;
    const int d     = blockIdx.y * 256 + threadIdx.x;
    const int l0    = chunk * CL;
    for (int i = threadIdx.x; i < CL; i += 256) { a_s[i] = a[l0 + i]; b_s[i] = bs[l0 + i]; }
    __syncthreads();
    if (blockIdx.y == 0 && threadIdx.x == 0) {
        float pp = 1.f;
        for (int i = 0; i < CL; ++i) { pp *= a_s[i]; P[l0 + i] = pp; }
    }
    float h = 0.f;
    u16* mp = m + (size_t)l0 * D_DIM + d;
    for (int i = 0; i < CL; ++i) {
        float mv = bf2f(mp[(size_t)i * D_DIM]);
        h = fmaf(a_s[i], h, b_s[i] * mv);
        mp[(size_t)i * D_DIM] = f2bf(h);
    }
}

__global__ void scan_carry(const u16* __restrict__ y, const float* __restrict__ P,
                           float* __restrict__ carry, int nchunks) {
    const int d = blockIdx.x * 256 + threadIdx.x;
    float H = 0.f;
    for (int c = 0; c < nchunks; ++c) {
        carry[(size_t)c * D_DIM + d] = H;
        const float Ac = P[c * CL + (CL - 1)];
        const float Bc = bf2f(y[((size_t)c * CL + (CL - 1)) * D_DIM + d]);
        H = fmaf(Ac, H, Bc);
    }
}

// ---------------------------------------------------------------------------
extern "C" void kernel_launch(void* const* d_in, const int* in_sizes, int n_in,
                              void* d_out, int out_size, void* d_ws, size_t ws_size,
                              hipStream_t stream) {
    const float* x  = (const float*)d_in[0];
    const float* Wq = (const float*)d_in[1];
    const float* Wk = (const float*)d_in[2];
    const float* Wr = (const float*)d_in[3];
    const float* We = (const float*)d_in[4];
    const float* Wm = (const float*)d_in[5];
    const float* Wd = (const float*)d_in[6];
    const int*   cu = (const int*)d_in[7];
    const int L    = in_sizes[0] / D_DIM;      // 32768
    const int nseq = in_sizes[7] - 1;          // 4

    const size_t LD2 = (size_t)L * D_DIM * 2;  // 64 MiB bf16 plane
    const size_t DD  = (size_t)D_DIM * D_DIM;
    const int nLD4 = L * D_DIM / 4;
    const int nDD4 = (int)(DD / 4);
    const int nchunks = L / CL;

    // ws: R1a x_hi -> z | R1b x_lo -> {Wdb,WmTb,WrTb,Wdmb,Wdrb} | R2a enc_hi
    //     R2b enc_lo | scalars (av, bs, P, carry)
    char* ws = (char*)d_ws;
    u16*   xh   = (u16*)ws;
    u16*   xl   = (u16*)(ws + LD2);
    u16*   zbuf = (u16*)ws;
    u16*   Wdb  = (u16*)(ws + LD2);                     // xl dead after enc
    u16*   WmTb = (u16*)(ws + LD2 + (2u << 20));
    u16*   WrTb = (u16*)(ws + LD2 + (4u << 20));
    u16*   Wdmb = (u16*)(ws + LD2 + (6u << 20));
    u16*   Wdrb = (u16*)(ws + LD2 + (8u << 20));
    u16*   ench = (u16*)(ws + 2 * LD2);
    u16*   encl = (u16*)(ws + 3 * LD2);
    float* av   = (float*)(ws + 4 * LD2);
    float* bs   = av + L;
    float* P    = bs + L;
    float* carry= P  + L;                      // [nchunks, D] = 256 KB

    // d_out scratch (ALL dead before the final gemm256<3> writes out):
    char* dob = (char*)d_out;
    u16* Weh   = (u16*)dob;
    u16* Wel   = (u16*)(dob + (2u << 20));
    u16* WqTh  = (u16*)(dob + (4u << 20));
    u16* WqTl  = (u16*)(dob + (6u << 20));
    u16* WkTh  = (u16*)(dob + (8u << 20));
    u16* WkTl  = (u16*)(dob + (10u << 20));
    float* Mf  = (float*)(dob + (12u << 20));
    u16* Mh    = (u16*)(dob + (16u << 20));
    u16* Ml    = (u16*)(dob + (18u << 20));
    u16* Wqb   = (u16*)(dob + (20u << 20));
    u16* Wkb   = (u16*)(dob + (22u << 20));
    float* partdot = (float*)(dob + (34u << 20));   // [16][L] = 2 MB
    float* partnq  = (float*)(dob + (36u << 20));
    float* partnk  = (float*)(dob + (38u << 20));
    float* out = (float*)d_out;

    dim3 gX3L(L / 128, D_DIM / 256);           // (256, 4)
    dim3 gX3D(D_DIM / 128, D_DIM / 256);       // (8, 4)
    dim3 g256(L / 256, D_DIM / 256);           // (128, 4)
    dim3 gD(D_DIM / 128, D_DIM / 128);         // (8, 8)
    dim3 gT(D_DIM / 32, D_DIM / 32);

    // 1. splits
    split_bf16<<<(nLD4 + 255) / 256, 256, 0, stream>>>(x, xh, xl, nLD4);
    split_bf16<<<(nDD4 + 255) / 256, 256, 0, stream>>>(We, Weh, Wel, nDD4);
    // 2. enc (x3) -> hi/lo planes
    gemm_x3<0><<<gX3L, 512, 0, stream>>>(xh, xl, Weh, Wel, nullptr, ench, encl,
                                         nullptr, nullptr, nullptr);
    // 3. M = Wq^T @ Wk (x3)
    transpose_split<<<gT, 256, 0, stream>>>(Wq, WqTh, WqTl);
    transpose_split<<<gT, 256, 0, stream>>>(Wk, WkTh, WkTl);
    gemm_x3<1><<<gX3D, 512, 0, stream>>>(WqTh, WqTl, WkTh, WkTl, Mf, nullptr, nullptr,
                                         nullptr, nullptr, nullptr);
    split_bf16<<<(nDD4 + 255) / 256, 256, 0, stream>>>(Mf, Mh, Ml, nDD4);
    // 4. fused t-GEMM + router dot partials (LDS-redistributed epilogue)
    gemm_x3<2><<<gX3L, 512, 0, stream>>>(ench, encl, Mh, Ml, nullptr, nullptr, nullptr,
                                         ench, encl, partdot);
    // 5. fused q,k norm partials
    conv_bf16<<<(nDD4 + 255) / 256, 256, 0, stream>>>(Wq, Wqb, nDD4);
    conv_bf16<<<(nDD4 + 255) / 256, 256, 0, stream>>>(Wk, Wkb, nDD4);
    norm2<<<gX3L, 512, 0, stream>>>(ench, Wqb, Wkb, partnq, partnk);
    // 6. combine partials -> p -> gates
    combine_router<<<(L + 255) / 256, 256, 0, stream>>>(partdot, partnq, partnk,
                                                        cu, nseq, av, bs, L);
    // 7. Wdm = Wd@Wm, Wdr = Wd@Wr (tiny; parked in ws R1b)
    conv_bf16<<<(nDD4 + 255) / 256, 256, 0, stream>>>(Wd, Wdb, nDD4);
    transpose_split<<<gT, 256, 0, stream>>>(Wm, WmTb, nullptr);
    transpose_split<<<gT, 256, 0, stream>>>(Wr, WrTb, nullptr);
    gemm_bf16_nt<<<gD, 256, 0, stream>>>(Wdb, WmTb, nullptr, Wdmb);
    gemm_bf16_nt<<<gD, 256, 0, stream>>>(Wdb, WrTb, nullptr, Wdrb);
    // 8. z = enc @ Wdm^T (bf16, over dead x_hi region)
    gemm256<0><<<g256, 512, 0, stream>>>(ench, Wdmb, nullptr, zbuf,
                                         nullptr, nullptr, nullptr);
    // 9. scan over z (decode-commuted)
    dim3 gsl(nchunks, D_DIM / 256);
    scan_local<<<gsl, 256, 0, stream>>>(av, bs, zbuf, P);
    scan_carry<<<D_DIM / 256, 256, 0, stream>>>(zbuf, P, carry, nchunks);
    // 10. out = enc @ Wdr^T + z_scanned + P*carry  (fused epilogue, f32 out)
    gemm256<3><<<g256, 512, 0, stream>>>(ench, Wdrb, out, nullptr,
                                         zbuf, P, carry);
}